// Round 16
// baseline (179.725 us; speedup 1.0000x reference)
//
#include <hip/hip_runtime.h>
#include <math.h>

#define INC   256
#define HIDALL 128   // HEADS*HID
#define HEADS 4
#define HID   32
#define NCLS  16
#define NEG   0.2f
#define BSH   9      // bucket = dst >> 9 (512 nodes per bucket)
#define MAXBUCK 128
#define BCAP  24576  // staging per-bucket capacity (mean fill 16384)
#define PCAP  40960  // esrc per-bucket padded capacity (>= BCAP + 512*31)
#define LOG2E 1.44269504088896340736f

typedef __attribute__((ext_vector_type(8))) short short8_t;
typedef __attribute__((ext_vector_type(4))) float f32x4_t;
typedef __attribute__((ext_vector_type(2))) float f32x2;

__device__ __forceinline__ float lrelu(float v) { return fmaxf(v, NEG * v); }

// bf16 helpers; lo = low half (exact), hi approximated by leaving garbage low bits
__device__ __forceinline__ float bflo(unsigned int v) { return __uint_as_float(v << 16); }
__device__ __forceinline__ float bfhi(unsigned int v) { return __uint_as_float(v & 0xFFFF0000u); }
__device__ __forceinline__ float bfhix(unsigned int v) { return __uint_as_float(v); }  // ~2^-8 rel err
__device__ __forceinline__ unsigned int f2bf(float f) {  // RNE round to bf16 (as u16)
  unsigned int v = __float_as_uint(f);
  return (v + 0x7FFFu + ((v >> 16) & 1u)) >> 16;
}
__device__ __forceinline__ unsigned int pack2(float a, float b) {
  return f2bf(a) | (f2bf(b) << 16);
}

// ---- one-time W1 repack + sentinel row init (as1 row N, h2x row N) ----------
__global__ void wt_k(const float* __restrict__ W, unsigned short* __restrict__ wtb,
                     float* __restrict__ as1, unsigned int* __restrict__ h2x, int n) {
  int i = blockIdx.x * 256 + threadIdx.x;  // 0..32767
  if (i < 4) as1[4 * (size_t)n + i] = -1e30f;     // agg1 sentinel: w = 0
  if (i >= 4 && i < 12) h2x[16 * (size_t)n + (i - 4)] = 0u;  // zero class pairs
  if (i == 12) h2x[16 * (size_t)n + 8] = __float_as_uint(-1e30f);  // agg2 sentinel
  int k = i >> 7, c = i & 127;
  wtb[(((k >> 5) * 4 + ((k >> 3) & 3)) * 128 + c) * 8 + (k & 7)] =
      (unsigned short)f2bf(W[i]);
}

// ------- GEMM1 (bf16 MFMA) + fused alpha1: h1(bf16) = x @ W1 -----------------
// alpha dots are pre-scaled by log2(e) so agg kernels can use exp2 directly.
#define GM 64
__global__ __launch_bounds__(256) void gemm1_k(const float* __restrict__ x,
                                               const unsigned short* __restrict__ wtb,
                                               const float* __restrict__ asrc,
                                               const float* __restrict__ adst,
                                               unsigned short* __restrict__ h1,
                                               float* __restrict__ as1,
                                               float* __restrict__ ad1, int Nrows) {
  __shared__ unsigned short xs2[4][GM][8];    // A tiles: [kgrp][row][k&7]
  __shared__ unsigned short wsm2[4][128][8];  // B tiles: [kgrp][col][k&7]
  __shared__ unsigned short hs[GM][128];      // C out-tile (bf16)
  __shared__ float attL[2 * HIDALL];          // asrc | adst
  int t = threadIdx.x;
  int m0 = blockIdx.x * GM;
  int w = t >> 6, lane = t & 63;
  if (t < HIDALL) attL[t] = asrc[t];
  else attL[t] = adst[t - HIDALL];

  f32x4_t acc[8];
#pragma unroll
  for (int ct = 0; ct < 8; ++ct) acc[ct] = (f32x4_t){0.f, 0.f, 0.f, 0.f};

  int rowA = w * 16 + (lane & 15);
  int kg = lane >> 4;
  int cl = lane & 15;

  for (int ks = 0; ks < 8; ++ks) {
    int kc = ks * 32;
#pragma unroll
    for (int jj = 0; jj < 2; ++jj) {
      int u = t + jj * 256;            // float4 unit
      int row = u >> 3, c4i = u & 7;   // k-offset = c4i*4
      int gr = m0 + row;
      float4 v = (gr < Nrows) ? *(const float4*)&x[(size_t)gr * INC + kc + c4i * 4]
                              : make_float4(0.f, 0.f, 0.f, 0.f);
      uint2 p;
      p.x = pack2(v.x, v.y);
      p.y = pack2(v.z, v.w);
      *(uint2*)&xs2[c4i >> 1][row][(c4i & 1) * 4] = p;
    }
    const unsigned short* wt = wtb + ks * 4096;
#pragma unroll
    for (int jj = 0; jj < 2; ++jj) {
      int u = t + jj * 256;
      *(uint4*)&((unsigned short*)wsm2)[u * 8] = *(const uint4*)&wt[u * 8];
    }
    __syncthreads();
    short8_t a = *(const short8_t*)&xs2[kg][rowA][0];
#pragma unroll
    for (int ct = 0; ct < 8; ++ct) {
      short8_t b = *(const short8_t*)&wsm2[kg][ct * 16 + cl][0];
      acc[ct] = __builtin_amdgcn_mfma_f32_16x16x32_bf16(a, b, acc[ct], 0, 0, 0);
    }
    __syncthreads();
  }
#pragma unroll
  for (int ct = 0; ct < 8; ++ct)
#pragma unroll
    for (int r = 0; r < 4; ++r)
      hs[w * 16 + (lane >> 4) * 4 + r][ct * 16 + cl] = (unsigned short)f2bf(acc[ct][r]);
  __syncthreads();
#pragma unroll
  for (int jj = 0; jj < 4; ++jj) {
    int u = t + jj * 256;
    int row = u >> 4, seg = u & 15;
    int gr = m0 + row;
    if (gr < Nrows)
      *(uint4*)&h1[(size_t)gr * HIDALL + seg * 8] = *(const uint4*)&hs[row][seg * 8];
  }
  {
    int row = t >> 2, h = t & 3;
    int gr = m0 + row;
    if (gr < Nrows) {
      float s = 0.f, dd = 0.f;
#pragma unroll
      for (int qq = 0; qq < 4; ++qq) {
        uint4 qv = *(const uint4*)&hs[row][h * 32 + qq * 8];
        int ab = h * 32 + qq * 8;
        s = fmaf(bflo(qv.x), attL[ab + 0], s);
        dd = fmaf(bflo(qv.x), attL[HIDALL + ab + 0], dd);
        s = fmaf(bfhi(qv.x), attL[ab + 1], s);
        dd = fmaf(bfhi(qv.x), attL[HIDALL + ab + 1], dd);
        s = fmaf(bflo(qv.y), attL[ab + 2], s);
        dd = fmaf(bflo(qv.y), attL[HIDALL + ab + 2], dd);
        s = fmaf(bfhi(qv.y), attL[ab + 3], s);
        dd = fmaf(bfhi(qv.y), attL[HIDALL + ab + 3], dd);
        s = fmaf(bflo(qv.z), attL[ab + 4], s);
        dd = fmaf(bflo(qv.z), attL[HIDALL + ab + 4], dd);
        s = fmaf(bfhi(qv.z), attL[ab + 5], s);
        dd = fmaf(bfhi(qv.z), attL[HIDALL + ab + 5], dd);
        s = fmaf(bflo(qv.w), attL[ab + 6], s);
        dd = fmaf(bflo(qv.w), attL[HIDALL + ab + 6], dd);
        s = fmaf(bfhi(qv.w), attL[ab + 7], s);
        dd = fmaf(bfhi(qv.w), attL[HIDALL + ab + 7], dd);
      }
      as1[(size_t)gr * 4 + h] = s * LOG2E;
      ad1[(size_t)gr * 4 + h] = dd * LOG2E;
    }
  }
}

// ------------ CSR build: fixed-capacity buckets (no histogram pass) ----------
#define S1_CH 8
__global__ __launch_bounds__(256) void stage1_k(const int* __restrict__ ei, int E,
                                                int* __restrict__ cursor,
                                                unsigned int* __restrict__ staging) {
  __shared__ int bh[MAXBUCK];
  __shared__ int bb[MAXBUCK];
  int t = threadIdx.x;
  if (t < MAXBUCK) bh[t] = 0;
  __syncthreads();
  int base = blockIdx.x * (256 * S1_CH);
  int s[S1_CH], d[S1_CH], r[S1_CH];
#pragma unroll
  for (int j = 0; j < S1_CH; ++j) {
    int e = base + t + j * 256;
    if (e < E) {
      s[j] = ei[e];
      d[j] = ei[(size_t)E + e];
      r[j] = atomicAdd(&bh[d[j] >> BSH], 1);
    } else {
      d[j] = -1;
    }
  }
  __syncthreads();
  if (t < MAXBUCK && bh[t]) bb[t] = atomicAdd(&cursor[t], bh[t]);
  __syncthreads();
#pragma unroll
  for (int j = 0; j < S1_CH; ++j) {
    if (d[j] >= 0) {
      int b = d[j] >> BSH;
      staging[(size_t)b * BCAP + bb[b] + r[j]] = ((unsigned)d[j] << 16) | (unsigned)s[j];
    }
  }
}

// stage 2: per bucket — degree count, padded scan -> rowptr/rowend, sentinel
// pad fill, then scatter. esrc stores src*128 (pre-scaled for agg addressing);
// pad slots hold sentinel n*128.
__global__ __launch_bounds__(1024) void stage2_k(const unsigned int* __restrict__ staging,
                                                 const int* __restrict__ cursor,
                                                 int* __restrict__ rowptr,
                                                 int* __restrict__ rowend,
                                                 int* __restrict__ esrc, int n) {
  __shared__ int cnt[1 << BSH];
  __shared__ int pfx[1 << BSH];
  __shared__ int curw[1 << BSH];
  int b = blockIdx.x, nb0 = b << BSH, t = threadIdx.x;
  if (t < (1 << BSH)) cnt[t] = 0;
  __syncthreads();
  int fill = cursor[b];
  const unsigned int* st = staging + (size_t)b * BCAP;
  for (int i = t; i < fill; i += 1024)
    atomicAdd(&cnt[(st[i] >> 16) - nb0], 1);
  __syncthreads();
  if (t < (1 << BSH)) pfx[t] = (cnt[t] + 31) & ~31;
  __syncthreads();
  for (int o = 1; o < (1 << BSH); o <<= 1) {
    int v = 0;
    if (t < (1 << BSH) && t >= o) v = pfx[t - o];
    __syncthreads();
    if (t < (1 << BSH)) pfx[t] += v;
    __syncthreads();
  }
  if (t < (1 << BSH)) {
    int padDeg = (cnt[t] + 31) & ~31;
    int rp = b * PCAP + pfx[t] - padDeg;  // exclusive prefix
    int node = nb0 + t;
    if (node < n) {
      rowptr[node] = rp;
      rowend[node] = rp + padDeg;
    }
    curw[t] = rp;
    for (int i = cnt[t]; i < padDeg; ++i) esrc[rp + i] = n << 7;  // sentinel
  }
  __syncthreads();
  for (int i = t; i < fill; i += 1024) {
    unsigned v = st[i];
    int pos = atomicAdd(&curw[(v >> 16) - nb0], 1);
    esrc[pos] = (int)(v & 0xFFFFu) << 7;  // src * 128
  }
}

// ------- layer-1 aggregate: 2 waves per node, one-pass, padded edge lists ----
// esrc pre-scaled by 128; weights via exp2 (alpha dots pre-scaled by log2 e).
#define A1PK(w_, u_)                                                            \
  {                                                                             \
    f32x2 wv = {w_, w_};                                                        \
    a2[0] = __builtin_elementwise_fma(wv, (f32x2){bflo(u_.x), bfhix(u_.x)}, a2[0]); \
    a2[1] = __builtin_elementwise_fma(wv, (f32x2){bflo(u_.y), bfhix(u_.y)}, a2[1]); \
    a2[2] = __builtin_elementwise_fma(wv, (f32x2){bflo(u_.z), bfhix(u_.z)}, a2[2]); \
    a2[3] = __builtin_elementwise_fma(wv, (f32x2){bflo(u_.w), bfhix(u_.w)}, a2[3]); \
  }

__global__ __launch_bounds__(256) void agg1_k(const int* __restrict__ rowptr,
                                              const int* __restrict__ rowend,
                                              const int* __restrict__ esrc,
                                              const unsigned short* __restrict__ h1,
                                              const float* __restrict__ as1,
                                              const float* __restrict__ ad1,
                                              const float* __restrict__ b1,
                                              unsigned short* __restrict__ hin2b, int n) {
  int wid = (blockIdx.x * 256 + threadIdx.x) >> 6;
  int lane = threadIdx.x & 63;
  if (wid >= 2 * n) return;
  int d = wid >> 1, half = wid & 1;
  int beg = rowptr[d], end = rowend[d];
  int fb8 = lane & 7, q = lane >> 3;
  int fOff = half * 64 + fb8 * 8;  // this lane's 8 features
  int h = half * 2 + (fb8 >> 2);   // head of those features
  float adv_h = ad1[4 * (size_t)d + h];
  float ws = exp2f(lrelu(as1[4 * (size_t)d + h] + adv_h));  // self weight
  float den = 0.f;
  f32x2 a2[4];
  a2[0] = a2[1] = a2[2] = a2[3] = (f32x2){0.f, 0.f};
  for (int i = beg + q; i < end; i += 32) {
    int s1 = esrc[i];        // = src1 * 128
    int s2 = esrc[i + 8];
    int s3 = esrc[i + 16];
    int s4 = esrc[i + 24];
    float av1 = as1[((size_t)s1 >> 5) + h];
    float av2 = as1[((size_t)s2 >> 5) + h];
    float av3 = as1[((size_t)s3 >> 5) + h];
    float av4 = as1[((size_t)s4 >> 5) + h];
    uint4 u1 = *(const uint4*)&h1[(size_t)s1 + fOff];
    uint4 u2 = *(const uint4*)&h1[(size_t)s2 + fOff];
    uint4 u3 = *(const uint4*)&h1[(size_t)s3 + fOff];
    uint4 u4 = *(const uint4*)&h1[(size_t)s4 + fOff];
    float w1 = exp2f(lrelu(av1 + adv_h));
    float w2 = exp2f(lrelu(av2 + adv_h));
    float w3 = exp2f(lrelu(av3 + adv_h));
    float w4 = exp2f(lrelu(av4 + adv_h));
    den += (w1 + w2) + (w3 + w4);
    A1PK(w1, u1)
    A1PK(w2, u2)
    A1PK(w3, u3)
    A1PK(w4, u4)
  }
  float a[8] = {a2[0].x, a2[0].y, a2[1].x, a2[1].y,
                a2[2].x, a2[2].y, a2[3].x, a2[3].y};
  // reduce den + features across the 8 q-groups (lane bits 3..5)
#pragma unroll
  for (int off = 8; off <= 32; off <<= 1) den += __shfl_xor(den, off);
#pragma unroll
  for (int j = 0; j < 8; j++) {
    a[j] += __shfl_xor(a[j], 8);
    a[j] += __shfl_xor(a[j], 16);
    a[j] += __shfl_xor(a[j], 32);
  }
  if (q == 0) {
    uint4 ud = *(const uint4*)&h1[(size_t)d * HIDALL + fOff];
    den += ws;
    float inv = 1.f / (den + 1e-16f);
    const float* bp = &b1[fOff];
    float4 bb0 = *(const float4*)bp;
    float4 bb1 = *(const float4*)(bp + 4);
    float v[8];
    v[0] = fmaf(ws, bflo(ud.x), a[0]) * inv + bb0.x;
    v[1] = fmaf(ws, bfhi(ud.x), a[1]) * inv + bb0.y;
    v[2] = fmaf(ws, bflo(ud.y), a[2]) * inv + bb0.z;
    v[3] = fmaf(ws, bfhi(ud.y), a[3]) * inv + bb0.w;
    v[4] = fmaf(ws, bflo(ud.z), a[4]) * inv + bb1.x;
    v[5] = fmaf(ws, bfhi(ud.z), a[5]) * inv + bb1.y;
    v[6] = fmaf(ws, bflo(ud.w), a[6]) * inv + bb1.z;
    v[7] = fmaf(ws, bfhi(ud.w), a[7]) * inv + bb1.w;
#pragma unroll
    for (int j = 0; j < 8; j++) v[j] = v[j] > 0.f ? v[j] : (__expf(v[j]) - 1.f);
    uint4 pv;
    pv.x = pack2(v[0], v[1]);
    pv.y = pack2(v[2], v[3]);
    pv.z = pack2(v[4], v[5]);
    pv.w = pack2(v[6], v[7]);
    *(uint4*)&hin2b[(size_t)d * HIDALL + fOff] = pv;
  }
}

// ------ GEMM2 (+alpha2): h2x packed rows = hin2b @ W2, [N,128]@[128,16] ------
// h2x row (16 uints = 64 B): [0..7] 8x packed bf16 class pairs, [8] as2*log2e.
__global__ __launch_bounds__(256) void gemm2_k(const unsigned short* __restrict__ hin2b,
                                               const float* __restrict__ W2,
                                               const float* __restrict__ a2s,
                                               const float* __restrict__ a2d,
                                               unsigned int* __restrict__ h2x,
                                               float* __restrict__ ad2, int n) {
  __shared__ float wsm[128 * 16];
  __shared__ float hs[16][129];
  int t = threadIdx.x;
#pragma unroll
  for (int j = 0; j < 8; j++) wsm[t + j * 256] = W2[t + j * 256];
  int n0 = blockIdx.x * 16;
  const unsigned int* hw = (const unsigned int*)hin2b;  // row = 64 uints
#pragma unroll
  for (int j = 0; j < 4; j++) {
    int u = t + j * 256;  // 0..1023
    int r = u >> 6, cu = u & 63;
    int gn = n0 + r;
    unsigned v = (gn < n) ? hw[(size_t)gn * 64 + cu] : 0u;
    hs[r][cu * 2] = bflo(v);
    hs[r][cu * 2 + 1] = bfhi(v);
  }
  __syncthreads();
  int nl = t >> 4, c = t & 15;
  int gn = n0 + nl;
  float acc = 0.f;
#pragma unroll
  for (int k = 0; k < 128; k++) acc = fmaf(hs[nl][k], wsm[k * 16 + c], acc);
  float ps = acc * a2s[c];
  float pd = acc * a2d[c];
#pragma unroll
  for (int off = 8; off; off >>= 1) {
    ps += __shfl_xor(ps, off);
    pd += __shfl_xor(pd, off);
  }
  float other = __shfl_xor(acc, 1);
  if (gn < n) {
    if ((c & 1) == 0) h2x[(size_t)gn * 16 + (c >> 1)] = pack2(acc, other);
    if (c == 0) {
      h2x[(size_t)gn * 16 + 8] = __float_as_uint(ps * LOG2E);
      ad2[gn] = pd * LOG2E;
    }
  }
}

// --- layer-2 aggregate: one line/edge + bias + log_softmax; 8 lanes x 2 cls --
__global__ __launch_bounds__(256) void agg2_k(const int* __restrict__ rowptr,
                                              const int* __restrict__ rowend,
                                              const int* __restrict__ esrc,
                                              const unsigned int* __restrict__ h2x,
                                              const float* __restrict__ ad2,
                                              const float* __restrict__ b2,
                                              float* __restrict__ out, int n) {
  int wid = (blockIdx.x * 256 + threadIdx.x) >> 6;
  int lane = threadIdx.x & 63;
  if (wid >= n) return;
  int d = wid;
  int beg = rowptr[d], end = rowend[d];
  int c2 = lane & 7, q = lane >> 3;
  float advd = ad2[d];
  float asd = __uint_as_float(h2x[(size_t)d * 16 + 8]);
  float ws = exp2f(lrelu(asd + advd));
  float den = 0.f, a0 = 0.f, a1 = 0.f;
  for (int i = beg + q; i < end; i += 16) {
    int sA = esrc[i];  // = srcA * 128
    const unsigned int* rA = &h2x[(size_t)sA >> 3];
    float avA = __uint_as_float(rA[8]);
    unsigned uA = rA[c2];
    int sB = esrc[i + 8];
    const unsigned int* rB = &h2x[(size_t)sB >> 3];
    float avB = __uint_as_float(rB[8]);
    unsigned uB = rB[c2];
    float wA = exp2f(lrelu(avA + advd));
    float wB = exp2f(lrelu(avB + advd));
    den += wA + wB;
    a0 = fmaf(wA, bflo(uA), a0); a1 = fmaf(wA, bfhix(uA), a1);
    a0 = fmaf(wB, bflo(uB), a0); a1 = fmaf(wB, bfhix(uB), a1);
  }
#pragma unroll
  for (int off = 8; off <= 32; off <<= 1) {
    den += __shfl_xor(den, off);
    a0 += __shfl_xor(a0, off);
    a1 += __shfl_xor(a1, off);
  }
  unsigned ud = h2x[(size_t)d * 16 + c2];
  den += ws;
  a0 = fmaf(ws, bflo(ud), a0);
  a1 = fmaf(ws, bfhi(ud), a1);
  float inv = 1.f / (den + 1e-16f);
  float l0 = a0 * inv + b2[2 * c2];
  float l1 = a1 * inv + b2[2 * c2 + 1];
  float m = fmaxf(l0, l1);
#pragma unroll
  for (int off = 1; off <= 4; off <<= 1) m = fmaxf(m, __shfl_xor(m, off));
  float se = __expf(l0 - m) + __expf(l1 - m);
#pragma unroll
  for (int off = 1; off <= 4; off <<= 1) se += __shfl_xor(se, off);
  float lg = logf(se);
  if (q == 0) {
    float2 r = make_float2(l0 - m - lg, l1 - m - lg);
    *(float2*)&out[(size_t)d * NCLS + 2 * c2] = r;
  }
}

extern "C" void kernel_launch(void* const* d_in, const int* in_sizes, int n_in,
                              void* d_out, int out_size, void* d_ws, size_t ws_size,
                              hipStream_t stream) {
  const float* x = (const float*)d_in[0];
  const int* ei = (const int*)d_in[1];  // int32 [2][E]: src row then dst row
  const float* W1 = (const float*)d_in[2];
  const float* asrc1 = (const float*)d_in[3];
  const float* adst1 = (const float*)d_in[4];
  const float* b1 = (const float*)d_in[5];
  const float* W2 = (const float*)d_in[6];
  const float* asrc2 = (const float*)d_in[7];
  const float* adst2 = (const float*)d_in[8];
  const float* b2 = (const float*)d_in[9];
  int N = in_sizes[0] / INC;  // 50000
  int E = in_sizes[1] / 2;    // 1600000
  float* out = (float*)d_out;
  int nbuck = (N + (1 << BSH) - 1) >> BSH;  // 98 for N=50000 (<= MAXBUCK)

  char* ws = (char*)d_ws;
  size_t off = 0;
  auto alloc = [&](size_t bytes) {
    void* p = ws + off;
    off = (off + bytes + 255) & ~(size_t)255;
    return p;
  };
  // h1/as1/h2x each have a sentinel row N (w=0 padding edges).
  unsigned short* h1 = (unsigned short*)alloc((size_t)(N + 1) * HIDALL * 2);
  unsigned short* hin2b = (unsigned short*)alloc((size_t)N * HIDALL * 2);
  float* as1 = (float*)alloc((size_t)(N + 1) * HEADS * 4);
  float* ad1 = (float*)alloc((size_t)N * HEADS * 4);
  unsigned int* h2x = (unsigned int*)alloc((size_t)(N + 1) * 16 * 4);
  float* ad2 = (float*)alloc((size_t)N * 4);
  int* rowptr = (int*)alloc((size_t)N * 4);
  int* rowend = (int*)alloc((size_t)N * 4);
  int* cursor = (int*)alloc(MAXBUCK * 4);
  int* esrc = (int*)alloc((size_t)MAXBUCK * PCAP * 4);
  unsigned int* staging = (unsigned int*)alloc((size_t)MAXBUCK * BCAP * 4);
  unsigned short* wtb = (unsigned short*)alloc((size_t)INC * HIDALL * 2);

  hipMemsetAsync(cursor, 0, MAXBUCK * 4, stream);
  wt_k<<<(INC * HIDALL) / 256, 256, 0, stream>>>(W1, wtb, as1, h2x, N);
  gemm1_k<<<(N + GM - 1) / GM, 256, 0, stream>>>(x, wtb, asrc1, adst1, h1, as1, ad1, N);
  stage1_k<<<(E + 256 * S1_CH - 1) / (256 * S1_CH), 256, 0, stream>>>(ei, E, cursor, staging);
  stage2_k<<<nbuck, 1024, 0, stream>>>(staging, cursor, rowptr, rowend, esrc, N);
  agg1_k<<<(2 * N + 3) / 4, 256, 0, stream>>>(rowptr, rowend, esrc, h1, as1, ad1, b1, hin2b, N);
  gemm2_k<<<(N + 15) / 16, 256, 0, stream>>>(hin2b, W2, asrc2, adst2, h2x, ad2, N);
  agg2_k<<<(N + 3) / 4, 256, 0, stream>>>(rowptr, rowend, esrc, h2x, ad2, b2, out, N);
}

// Round 17
// 177.865 us; speedup vs baseline: 1.0105x; 1.0105x over previous
//
#include <hip/hip_runtime.h>
#include <math.h>

#define INC   256
#define HIDALL 128   // HEADS*HID
#define HEADS 4
#define HID   32
#define NCLS  16
#define NEG   0.2f
#define BSH   9      // bucket = dst >> 9 (512 nodes per bucket)
#define MAXBUCK 128
#define BCAP  24576  // staging per-bucket capacity (mean fill 16384)
#define PCAP  40960  // esrc per-bucket padded capacity (>= BCAP + 512*31)
#define LOG2E 1.44269504088896340736f

typedef __attribute__((ext_vector_type(8))) short short8_t;
typedef __attribute__((ext_vector_type(4))) float f32x4_t;
typedef __attribute__((ext_vector_type(2))) float f32x2;

__device__ __forceinline__ float lrelu(float v) { return fmaxf(v, NEG * v); }
__device__ __forceinline__ float fexp2(float v) { return __builtin_amdgcn_exp2f(v); }

// bf16 helpers; lo = low half (exact), hi approximated by leaving garbage low bits
__device__ __forceinline__ float bflo(unsigned int v) { return __uint_as_float(v << 16); }
__device__ __forceinline__ float bfhi(unsigned int v) { return __uint_as_float(v & 0xFFFF0000u); }
__device__ __forceinline__ float bfhix(unsigned int v) { return __uint_as_float(v); }  // ~2^-8 rel err
__device__ __forceinline__ unsigned int f2bf(float f) {  // RNE round to bf16 (as u16)
  unsigned int v = __float_as_uint(f);
  return (v + 0x7FFFu + ((v >> 16) & 1u)) >> 16;
}
__device__ __forceinline__ unsigned int pack2(float a, float b) {
  return f2bf(a) | (f2bf(b) << 16);
}

// ---- one-time W1 repack + sentinel row init (as1 row N, h2x row N) ----------
__global__ void wt_k(const float* __restrict__ W, unsigned short* __restrict__ wtb,
                     float* __restrict__ as1, unsigned int* __restrict__ h2x, int n) {
  int i = blockIdx.x * 256 + threadIdx.x;  // 0..32767
  if (i < 4) as1[4 * (size_t)n + i] = -1e30f;     // agg1 sentinel: w = 0
  if (i >= 4 && i < 12) h2x[16 * (size_t)n + (i - 4)] = 0u;  // zero class pairs
  if (i == 12) h2x[16 * (size_t)n + 8] = __float_as_uint(-1e30f);  // agg2 sentinel
  int k = i >> 7, c = i & 127;
  wtb[(((k >> 5) * 4 + ((k >> 3) & 3)) * 128 + c) * 8 + (k & 7)] =
      (unsigned short)f2bf(W[i]);
}

// ------- GEMM1 (bf16 MFMA) + fused alpha1: h1(bf16) = x @ W1 -----------------
// alpha dots are pre-scaled by log2(e) so agg kernels can use raw v_exp_f32.
#define GM 64
__global__ __launch_bounds__(256) void gemm1_k(const float* __restrict__ x,
                                               const unsigned short* __restrict__ wtb,
                                               const float* __restrict__ asrc,
                                               const float* __restrict__ adst,
                                               unsigned short* __restrict__ h1,
                                               float* __restrict__ as1,
                                               float* __restrict__ ad1, int Nrows) {
  __shared__ unsigned short xs2[4][GM][8];    // A tiles: [kgrp][row][k&7]
  __shared__ unsigned short wsm2[4][128][8];  // B tiles: [kgrp][col][k&7]
  __shared__ unsigned short hs[GM][128];      // C out-tile (bf16)
  __shared__ float attL[2 * HIDALL];          // asrc | adst
  int t = threadIdx.x;
  int m0 = blockIdx.x * GM;
  int w = t >> 6, lane = t & 63;
  if (t < HIDALL) attL[t] = asrc[t];
  else attL[t] = adst[t - HIDALL];

  f32x4_t acc[8];
#pragma unroll
  for (int ct = 0; ct < 8; ++ct) acc[ct] = (f32x4_t){0.f, 0.f, 0.f, 0.f};

  int rowA = w * 16 + (lane & 15);
  int kg = lane >> 4;
  int cl = lane & 15;

  for (int ks = 0; ks < 8; ++ks) {
    int kc = ks * 32;
#pragma unroll
    for (int jj = 0; jj < 2; ++jj) {
      int u = t + jj * 256;            // float4 unit
      int row = u >> 3, c4i = u & 7;   // k-offset = c4i*4
      int gr = m0 + row;
      float4 v = (gr < Nrows) ? *(const float4*)&x[(size_t)gr * INC + kc + c4i * 4]
                              : make_float4(0.f, 0.f, 0.f, 0.f);
      uint2 p;
      p.x = pack2(v.x, v.y);
      p.y = pack2(v.z, v.w);
      *(uint2*)&xs2[c4i >> 1][row][(c4i & 1) * 4] = p;
    }
    const unsigned short* wt = wtb + ks * 4096;
#pragma unroll
    for (int jj = 0; jj < 2; ++jj) {
      int u = t + jj * 256;
      *(uint4*)&((unsigned short*)wsm2)[u * 8] = *(const uint4*)&wt[u * 8];
    }
    __syncthreads();
    short8_t a = *(const short8_t*)&xs2[kg][rowA][0];
#pragma unroll
    for (int ct = 0; ct < 8; ++ct) {
      short8_t b = *(const short8_t*)&wsm2[kg][ct * 16 + cl][0];
      acc[ct] = __builtin_amdgcn_mfma_f32_16x16x32_bf16(a, b, acc[ct], 0, 0, 0);
    }
    __syncthreads();
  }
#pragma unroll
  for (int ct = 0; ct < 8; ++ct)
#pragma unroll
    for (int r = 0; r < 4; ++r)
      hs[w * 16 + (lane >> 4) * 4 + r][ct * 16 + cl] = (unsigned short)f2bf(acc[ct][r]);
  __syncthreads();
#pragma unroll
  for (int jj = 0; jj < 4; ++jj) {
    int u = t + jj * 256;
    int row = u >> 4, seg = u & 15;
    int gr = m0 + row;
    if (gr < Nrows)
      *(uint4*)&h1[(size_t)gr * HIDALL + seg * 8] = *(const uint4*)&hs[row][seg * 8];
  }
  {
    int row = t >> 2, h = t & 3;
    int gr = m0 + row;
    if (gr < Nrows) {
      float s = 0.f, dd = 0.f;
#pragma unroll
      for (int qq = 0; qq < 4; ++qq) {
        uint4 qv = *(const uint4*)&hs[row][h * 32 + qq * 8];
        int ab = h * 32 + qq * 8;
        s = fmaf(bflo(qv.x), attL[ab + 0], s);
        dd = fmaf(bflo(qv.x), attL[HIDALL + ab + 0], dd);
        s = fmaf(bfhi(qv.x), attL[ab + 1], s);
        dd = fmaf(bfhi(qv.x), attL[HIDALL + ab + 1], dd);
        s = fmaf(bflo(qv.y), attL[ab + 2], s);
        dd = fmaf(bflo(qv.y), attL[HIDALL + ab + 2], dd);
        s = fmaf(bfhi(qv.y), attL[ab + 3], s);
        dd = fmaf(bfhi(qv.y), attL[HIDALL + ab + 3], dd);
        s = fmaf(bflo(qv.z), attL[ab + 4], s);
        dd = fmaf(bflo(qv.z), attL[HIDALL + ab + 4], dd);
        s = fmaf(bfhi(qv.z), attL[ab + 5], s);
        dd = fmaf(bfhi(qv.z), attL[HIDALL + ab + 5], dd);
        s = fmaf(bflo(qv.w), attL[ab + 6], s);
        dd = fmaf(bflo(qv.w), attL[HIDALL + ab + 6], dd);
        s = fmaf(bfhi(qv.w), attL[ab + 7], s);
        dd = fmaf(bfhi(qv.w), attL[HIDALL + ab + 7], dd);
      }
      as1[(size_t)gr * 4 + h] = s * LOG2E;
      ad1[(size_t)gr * 4 + h] = dd * LOG2E;
    }
  }
}

// ------------ CSR build: fixed-capacity buckets (no histogram pass) ----------
#define S1_CH 8
__global__ __launch_bounds__(256) void stage1_k(const int* __restrict__ ei, int E,
                                                int* __restrict__ cursor,
                                                unsigned int* __restrict__ staging) {
  __shared__ int bh[MAXBUCK];
  __shared__ int bb[MAXBUCK];
  int t = threadIdx.x;
  if (t < MAXBUCK) bh[t] = 0;
  __syncthreads();
  int base = blockIdx.x * (256 * S1_CH);
  int s[S1_CH], d[S1_CH], r[S1_CH];
#pragma unroll
  for (int j = 0; j < S1_CH; ++j) {
    int e = base + t + j * 256;
    if (e < E) {
      s[j] = ei[e];
      d[j] = ei[(size_t)E + e];
      r[j] = atomicAdd(&bh[d[j] >> BSH], 1);
    } else {
      d[j] = -1;
    }
  }
  __syncthreads();
  if (t < MAXBUCK && bh[t]) bb[t] = atomicAdd(&cursor[t], bh[t]);
  __syncthreads();
#pragma unroll
  for (int j = 0; j < S1_CH; ++j) {
    if (d[j] >= 0) {
      int b = d[j] >> BSH;
      staging[(size_t)b * BCAP + bb[b] + r[j]] = ((unsigned)d[j] << 16) | (unsigned)s[j];
    }
  }
}

// stage 2: per bucket — degree count, padded scan -> rowptr/rowend, sentinel
// pad fill, then scatter. esrc stores src*128 (pre-scaled for agg addressing);
// pad slots hold sentinel n*128.
__global__ __launch_bounds__(1024) void stage2_k(const unsigned int* __restrict__ staging,
                                                 const int* __restrict__ cursor,
                                                 int* __restrict__ rowptr,
                                                 int* __restrict__ rowend,
                                                 int* __restrict__ esrc, int n) {
  __shared__ int cnt[1 << BSH];
  __shared__ int pfx[1 << BSH];
  __shared__ int curw[1 << BSH];
  int b = blockIdx.x, nb0 = b << BSH, t = threadIdx.x;
  if (t < (1 << BSH)) cnt[t] = 0;
  __syncthreads();
  int fill = cursor[b];
  const unsigned int* st = staging + (size_t)b * BCAP;
  for (int i = t; i < fill; i += 1024)
    atomicAdd(&cnt[(st[i] >> 16) - nb0], 1);
  __syncthreads();
  if (t < (1 << BSH)) pfx[t] = (cnt[t] + 31) & ~31;
  __syncthreads();
  for (int o = 1; o < (1 << BSH); o <<= 1) {
    int v = 0;
    if (t < (1 << BSH) && t >= o) v = pfx[t - o];
    __syncthreads();
    if (t < (1 << BSH)) pfx[t] += v;
    __syncthreads();
  }
  if (t < (1 << BSH)) {
    int padDeg = (cnt[t] + 31) & ~31;
    int rp = b * PCAP + pfx[t] - padDeg;  // exclusive prefix
    int node = nb0 + t;
    if (node < n) {
      rowptr[node] = rp;
      rowend[node] = rp + padDeg;
    }
    curw[t] = rp;
    for (int i = cnt[t]; i < padDeg; ++i) esrc[rp + i] = n << 7;  // sentinel
  }
  __syncthreads();
  for (int i = t; i < fill; i += 1024) {
    unsigned v = st[i];
    int pos = atomicAdd(&curw[(v >> 16) - nb0], 1);
    esrc[pos] = (int)(v & 0xFFFFu) << 7;  // src * 128
  }
}

// ------- layer-1 aggregate: 2 waves per node, one-pass, padded edge lists ----
// esrc pre-scaled by 128; weights via raw v_exp_f32 (dots pre-scaled by log2 e).
#define A1PK(w_, u_)                                                            \
  {                                                                             \
    f32x2 wv = {w_, w_};                                                        \
    a2[0] = __builtin_elementwise_fma(wv, (f32x2){bflo(u_.x), bfhix(u_.x)}, a2[0]); \
    a2[1] = __builtin_elementwise_fma(wv, (f32x2){bflo(u_.y), bfhix(u_.y)}, a2[1]); \
    a2[2] = __builtin_elementwise_fma(wv, (f32x2){bflo(u_.z), bfhix(u_.z)}, a2[2]); \
    a2[3] = __builtin_elementwise_fma(wv, (f32x2){bflo(u_.w), bfhix(u_.w)}, a2[3]); \
  }

__global__ __launch_bounds__(256) void agg1_k(const int* __restrict__ rowptr,
                                              const int* __restrict__ rowend,
                                              const int* __restrict__ esrc,
                                              const unsigned short* __restrict__ h1,
                                              const float* __restrict__ as1,
                                              const float* __restrict__ ad1,
                                              const float* __restrict__ b1,
                                              unsigned short* __restrict__ hin2b, int n) {
  int wid = (blockIdx.x * 256 + threadIdx.x) >> 6;
  int lane = threadIdx.x & 63;
  if (wid >= 2 * n) return;
  int d = wid >> 1, half = wid & 1;
  int beg = rowptr[d], end = rowend[d];
  int fb8 = lane & 7, q = lane >> 3;
  int fOff = half * 64 + fb8 * 8;  // this lane's 8 features
  int h = half * 2 + (fb8 >> 2);   // head of those features
  float adv_h = ad1[4 * (size_t)d + h];
  float ws = fexp2(lrelu(as1[4 * (size_t)d + h] + adv_h));  // self weight
  float den = 0.f;
  f32x2 a2[4];
  a2[0] = a2[1] = a2[2] = a2[3] = (f32x2){0.f, 0.f};
  for (int i = beg + q; i < end; i += 32) {
    int s1 = esrc[i];        // = src1 * 128
    int s2 = esrc[i + 8];
    int s3 = esrc[i + 16];
    int s4 = esrc[i + 24];
    float av1 = as1[((size_t)s1 >> 5) + h];
    float av2 = as1[((size_t)s2 >> 5) + h];
    float av3 = as1[((size_t)s3 >> 5) + h];
    float av4 = as1[((size_t)s4 >> 5) + h];
    uint4 u1 = *(const uint4*)&h1[(size_t)s1 + fOff];
    uint4 u2 = *(const uint4*)&h1[(size_t)s2 + fOff];
    uint4 u3 = *(const uint4*)&h1[(size_t)s3 + fOff];
    uint4 u4 = *(const uint4*)&h1[(size_t)s4 + fOff];
    float w1 = fexp2(lrelu(av1 + adv_h));
    float w2 = fexp2(lrelu(av2 + adv_h));
    float w3 = fexp2(lrelu(av3 + adv_h));
    float w4 = fexp2(lrelu(av4 + adv_h));
    den += (w1 + w2) + (w3 + w4);
    A1PK(w1, u1)
    A1PK(w2, u2)
    A1PK(w3, u3)
    A1PK(w4, u4)
  }
  float a[8] = {a2[0].x, a2[0].y, a2[1].x, a2[1].y,
                a2[2].x, a2[2].y, a2[3].x, a2[3].y};
  // reduce den + features across the 8 q-groups (lane bits 3..5)
#pragma unroll
  for (int off = 8; off <= 32; off <<= 1) den += __shfl_xor(den, off);
#pragma unroll
  for (int j = 0; j < 8; j++) {
    a[j] += __shfl_xor(a[j], 8);
    a[j] += __shfl_xor(a[j], 16);
    a[j] += __shfl_xor(a[j], 32);
  }
  if (q == 0) {
    uint4 ud = *(const uint4*)&h1[(size_t)d * HIDALL + fOff];
    den += ws;
    float inv = 1.f / (den + 1e-16f);
    const float* bp = &b1[fOff];
    float4 bb0 = *(const float4*)bp;
    float4 bb1 = *(const float4*)(bp + 4);
    float v[8];
    v[0] = fmaf(ws, bflo(ud.x), a[0]) * inv + bb0.x;
    v[1] = fmaf(ws, bfhi(ud.x), a[1]) * inv + bb0.y;
    v[2] = fmaf(ws, bflo(ud.y), a[2]) * inv + bb0.z;
    v[3] = fmaf(ws, bfhi(ud.y), a[3]) * inv + bb0.w;
    v[4] = fmaf(ws, bflo(ud.z), a[4]) * inv + bb1.x;
    v[5] = fmaf(ws, bfhi(ud.z), a[5]) * inv + bb1.y;
    v[6] = fmaf(ws, bflo(ud.w), a[6]) * inv + bb1.z;
    v[7] = fmaf(ws, bfhi(ud.w), a[7]) * inv + bb1.w;
#pragma unroll
    for (int j = 0; j < 8; j++) v[j] = v[j] > 0.f ? v[j] : (__expf(v[j]) - 1.f);
    uint4 pv;
    pv.x = pack2(v[0], v[1]);
    pv.y = pack2(v[2], v[3]);
    pv.z = pack2(v[4], v[5]);
    pv.w = pack2(v[6], v[7]);
    *(uint4*)&hin2b[(size_t)d * HIDALL + fOff] = pv;
  }
}

// ------ GEMM2 (+alpha2): h2x packed rows = hin2b @ W2, [N,128]@[128,16] ------
// h2x row (16 uints = 64 B): [0..7] 8x packed bf16 class pairs, [8] as2*log2e.
__global__ __launch_bounds__(256) void gemm2_k(const unsigned short* __restrict__ hin2b,
                                               const float* __restrict__ W2,
                                               const float* __restrict__ a2s,
                                               const float* __restrict__ a2d,
                                               unsigned int* __restrict__ h2x,
                                               float* __restrict__ ad2, int n) {
  __shared__ float wsm[128 * 16];
  __shared__ float hs[16][129];
  int t = threadIdx.x;
#pragma unroll
  for (int j = 0; j < 8; j++) wsm[t + j * 256] = W2[t + j * 256];
  int n0 = blockIdx.x * 16;
  const unsigned int* hw = (const unsigned int*)hin2b;  // row = 64 uints
#pragma unroll
  for (int j = 0; j < 4; j++) {
    int u = t + j * 256;  // 0..1023
    int r = u >> 6, cu = u & 63;
    int gn = n0 + r;
    unsigned v = (gn < n) ? hw[(size_t)gn * 64 + cu] : 0u;
    hs[r][cu * 2] = bflo(v);
    hs[r][cu * 2 + 1] = bfhi(v);
  }
  __syncthreads();
  int nl = t >> 4, c = t & 15;
  int gn = n0 + nl;
  float acc = 0.f;
#pragma unroll
  for (int k = 0; k < 128; k++) acc = fmaf(hs[nl][k], wsm[k * 16 + c], acc);
  float ps = acc * a2s[c];
  float pd = acc * a2d[c];
#pragma unroll
  for (int off = 8; off; off >>= 1) {
    ps += __shfl_xor(ps, off);
    pd += __shfl_xor(pd, off);
  }
  float other = __shfl_xor(acc, 1);
  if (gn < n) {
    if ((c & 1) == 0) h2x[(size_t)gn * 16 + (c >> 1)] = pack2(acc, other);
    if (c == 0) {
      h2x[(size_t)gn * 16 + 8] = __float_as_uint(ps * LOG2E);
      ad2[gn] = pd * LOG2E;
    }
  }
}

// --- layer-2 aggregate: one line/edge + bias + log_softmax; 8 lanes x 2 cls --
__global__ __launch_bounds__(256) void agg2_k(const int* __restrict__ rowptr,
                                              const int* __restrict__ rowend,
                                              const int* __restrict__ esrc,
                                              const unsigned int* __restrict__ h2x,
                                              const float* __restrict__ ad2,
                                              const float* __restrict__ b2,
                                              float* __restrict__ out, int n) {
  int wid = (blockIdx.x * 256 + threadIdx.x) >> 6;
  int lane = threadIdx.x & 63;
  if (wid >= n) return;
  int d = wid;
  int beg = rowptr[d], end = rowend[d];
  int c2 = lane & 7, q = lane >> 3;
  float advd = ad2[d];
  float asd = __uint_as_float(h2x[(size_t)d * 16 + 8]);
  float ws = fexp2(lrelu(asd + advd));
  float den = 0.f, a0 = 0.f, a1 = 0.f;
  for (int i = beg + q; i < end; i += 16) {
    int sA = esrc[i];  // = srcA * 128
    const unsigned int* rA = &h2x[(size_t)sA >> 3];
    float avA = __uint_as_float(rA[8]);
    unsigned uA = rA[c2];
    int sB = esrc[i + 8];
    const unsigned int* rB = &h2x[(size_t)sB >> 3];
    float avB = __uint_as_float(rB[8]);
    unsigned uB = rB[c2];
    float wA = fexp2(lrelu(avA + advd));
    float wB = fexp2(lrelu(avB + advd));
    den += wA + wB;
    a0 = fmaf(wA, bflo(uA), a0); a1 = fmaf(wA, bfhix(uA), a1);
    a0 = fmaf(wB, bflo(uB), a0); a1 = fmaf(wB, bfhix(uB), a1);
  }
#pragma unroll
  for (int off = 8; off <= 32; off <<= 1) {
    den += __shfl_xor(den, off);
    a0 += __shfl_xor(a0, off);
    a1 += __shfl_xor(a1, off);
  }
  unsigned ud = h2x[(size_t)d * 16 + c2];
  den += ws;
  a0 = fmaf(ws, bflo(ud), a0);
  a1 = fmaf(ws, bfhi(ud), a1);
  float inv = 1.f / (den + 1e-16f);
  float l0 = a0 * inv + b2[2 * c2];
  float l1 = a1 * inv + b2[2 * c2 + 1];
  float m = fmaxf(l0, l1);
#pragma unroll
  for (int off = 1; off <= 4; off <<= 1) m = fmaxf(m, __shfl_xor(m, off));
  float se = __expf(l0 - m) + __expf(l1 - m);
#pragma unroll
  for (int off = 1; off <= 4; off <<= 1) se += __shfl_xor(se, off);
  float lg = logf(se);
  if (q == 0) {
    float2 r = make_float2(l0 - m - lg, l1 - m - lg);
    *(float2*)&out[(size_t)d * NCLS + 2 * c2] = r;
  }
}

extern "C" void kernel_launch(void* const* d_in, const int* in_sizes, int n_in,
                              void* d_out, int out_size, void* d_ws, size_t ws_size,
                              hipStream_t stream) {
  const float* x = (const float*)d_in[0];
  const int* ei = (const int*)d_in[1];  // int32 [2][E]: src row then dst row
  const float* W1 = (const float*)d_in[2];
  const float* asrc1 = (const float*)d_in[3];
  const float* adst1 = (const float*)d_in[4];
  const float* b1 = (const float*)d_in[5];
  const float* W2 = (const float*)d_in[6];
  const float* asrc2 = (const float*)d_in[7];
  const float* adst2 = (const float*)d_in[8];
  const float* b2 = (const float*)d_in[9];
  int N = in_sizes[0] / INC;  // 50000
  int E = in_sizes[1] / 2;    // 1600000
  float* out = (float*)d_out;
  int nbuck = (N + (1 << BSH) - 1) >> BSH;  // 98 for N=50000 (<= MAXBUCK)

  char* ws = (char*)d_ws;
  size_t off = 0;
  auto alloc = [&](size_t bytes) {
    void* p = ws + off;
    off = (off + bytes + 255) & ~(size_t)255;
    return p;
  };
  // h1/as1/h2x each have a sentinel row N (w=0 padding edges).
  unsigned short* h1 = (unsigned short*)alloc((size_t)(N + 1) * HIDALL * 2);
  unsigned short* hin2b = (unsigned short*)alloc((size_t)N * HIDALL * 2);
  float* as1 = (float*)alloc((size_t)(N + 1) * HEADS * 4);
  float* ad1 = (float*)alloc((size_t)N * HEADS * 4);
  unsigned int* h2x = (unsigned int*)alloc((size_t)(N + 1) * 16 * 4);
  float* ad2 = (float*)alloc((size_t)N * 4);
  int* rowptr = (int*)alloc((size_t)N * 4);
  int* rowend = (int*)alloc((size_t)N * 4);
  int* cursor = (int*)alloc(MAXBUCK * 4);
  int* esrc = (int*)alloc((size_t)MAXBUCK * PCAP * 4);
  unsigned int* staging = (unsigned int*)alloc((size_t)MAXBUCK * BCAP * 4);
  unsigned short* wtb = (unsigned short*)alloc((size_t)INC * HIDALL * 2);

  hipMemsetAsync(cursor, 0, MAXBUCK * 4, stream);
  wt_k<<<(INC * HIDALL) / 256, 256, 0, stream>>>(W1, wtb, as1, h2x, N);
  gemm1_k<<<(N + GM - 1) / GM, 256, 0, stream>>>(x, wtb, asrc1, adst1, h1, as1, ad1, N);
  stage1_k<<<(E + 256 * S1_CH - 1) / (256 * S1_CH), 256, 0, stream>>>(ei, E, cursor, staging);
  stage2_k<<<nbuck, 1024, 0, stream>>>(staging, cursor, rowptr, rowend, esrc, N);
  agg1_k<<<(2 * N + 3) / 4, 256, 0, stream>>>(rowptr, rowend, esrc, h1, as1, ad1, b1, hin2b, N);
  gemm2_k<<<(N + 15) / 16, 256, 0, stream>>>(hin2b, W2, asrc2, adst2, h2x, ad2, N);
  agg2_k<<<(N + 3) / 4, 256, 0, stream>>>(rowptr, rowend, esrc, h2x, ad2, b2, out, N);
}

// Round 18
// 174.703 us; speedup vs baseline: 1.0287x; 1.0181x over previous
//
#include <hip/hip_runtime.h>
#include <math.h>

#define INC   256
#define HIDALL 128   // HEADS*HID
#define HEADS 4
#define HID   32
#define NCLS  16
#define NEG   0.2f
#define BSH   9      // bucket = dst >> 9 (512 nodes per bucket)
#define MAXBUCK 128
#define BCAP  24576  // staging per-bucket capacity (mean fill 16384)
#define PCAP  40960  // esrc per-bucket padded capacity
#define LOG2E 1.44269504088896340736f

typedef __attribute__((ext_vector_type(8))) short short8_t;
typedef __attribute__((ext_vector_type(4))) float f32x4_t;
typedef __attribute__((ext_vector_type(2))) float f32x2;

__device__ __forceinline__ float lrelu(float v) { return fmaxf(v, NEG * v); }
__device__ __forceinline__ float fexp2(float v) { return __builtin_amdgcn_exp2f(v); }

// bf16 helpers; lo = low half (exact), hi approximated by leaving garbage low bits
__device__ __forceinline__ float bflo(unsigned int v) { return __uint_as_float(v << 16); }
__device__ __forceinline__ float bfhi(unsigned int v) { return __uint_as_float(v & 0xFFFF0000u); }
__device__ __forceinline__ float bfhix(unsigned int v) { return __uint_as_float(v); }  // ~2^-8 rel err
__device__ __forceinline__ unsigned int f2bf(float f) {  // RNE round to bf16 (as u16)
  unsigned int v = __float_as_uint(f);
  return (v + 0x7FFFu + ((v >> 16) & 1u)) >> 16;
}
__device__ __forceinline__ unsigned int pack2(float a, float b) {
  return f2bf(a) | (f2bf(b) << 16);
}

// ---- one-time W1 repack + sentinel row init (as1 row N, h2x row N) ----------
__global__ void wt_k(const float* __restrict__ W, unsigned short* __restrict__ wtb,
                     float* __restrict__ as1, unsigned int* __restrict__ h2x, int n) {
  int i = blockIdx.x * 256 + threadIdx.x;  // 0..32767
  if (i < 4) as1[4 * (size_t)n + i] = -1e30f;     // agg1 sentinel: w = 0
  if (i >= 4 && i < 12) h2x[16 * (size_t)n + (i - 4)] = 0u;  // zero class pairs
  if (i == 12) h2x[16 * (size_t)n + 8] = __float_as_uint(-1e30f);  // agg2 sentinel
  int k = i >> 7, c = i & 127;
  wtb[(((k >> 5) * 4 + ((k >> 3) & 3)) * 128 + c) * 8 + (k & 7)] =
      (unsigned short)f2bf(W[i]);
}

// ------- GEMM1 (bf16 MFMA) + fused alpha1: h1(bf16) = x @ W1 -----------------
// alpha dots are pre-scaled by log2(e) so agg kernels can use raw v_exp_f32.
#define GM 64
__global__ __launch_bounds__(256) void gemm1_k(const float* __restrict__ x,
                                               const unsigned short* __restrict__ wtb,
                                               const float* __restrict__ asrc,
                                               const float* __restrict__ adst,
                                               unsigned short* __restrict__ h1,
                                               float* __restrict__ as1,
                                               float* __restrict__ ad1, int Nrows) {
  __shared__ unsigned short xs2[4][GM][8];    // A tiles: [kgrp][row][k&7]
  __shared__ unsigned short wsm2[4][128][8];  // B tiles: [kgrp][col][k&7]
  __shared__ unsigned short hs[GM][128];      // C out-tile (bf16)
  __shared__ float attL[2 * HIDALL];          // asrc | adst
  int t = threadIdx.x;
  int m0 = blockIdx.x * GM;
  int w = t >> 6, lane = t & 63;
  if (t < HIDALL) attL[t] = asrc[t];
  else attL[t] = adst[t - HIDALL];

  f32x4_t acc[8];
#pragma unroll
  for (int ct = 0; ct < 8; ++ct) acc[ct] = (f32x4_t){0.f, 0.f, 0.f, 0.f};

  int rowA = w * 16 + (lane & 15);
  int kg = lane >> 4;
  int cl = lane & 15;

  for (int ks = 0; ks < 8; ++ks) {
    int kc = ks * 32;
#pragma unroll
    for (int jj = 0; jj < 2; ++jj) {
      int u = t + jj * 256;            // float4 unit
      int row = u >> 3, c4i = u & 7;   // k-offset = c4i*4
      int gr = m0 + row;
      float4 v = (gr < Nrows) ? *(const float4*)&x[(size_t)gr * INC + kc + c4i * 4]
                              : make_float4(0.f, 0.f, 0.f, 0.f);
      uint2 p;
      p.x = pack2(v.x, v.y);
      p.y = pack2(v.z, v.w);
      *(uint2*)&xs2[c4i >> 1][row][(c4i & 1) * 4] = p;
    }
    const unsigned short* wt = wtb + ks * 4096;
#pragma unroll
    for (int jj = 0; jj < 2; ++jj) {
      int u = t + jj * 256;
      *(uint4*)&((unsigned short*)wsm2)[u * 8] = *(const uint4*)&wt[u * 8];
    }
    __syncthreads();
    short8_t a = *(const short8_t*)&xs2[kg][rowA][0];
#pragma unroll
    for (int ct = 0; ct < 8; ++ct) {
      short8_t b = *(const short8_t*)&wsm2[kg][ct * 16 + cl][0];
      acc[ct] = __builtin_amdgcn_mfma_f32_16x16x32_bf16(a, b, acc[ct], 0, 0, 0);
    }
    __syncthreads();
  }
#pragma unroll
  for (int ct = 0; ct < 8; ++ct)
#pragma unroll
    for (int r = 0; r < 4; ++r)
      hs[w * 16 + (lane >> 4) * 4 + r][ct * 16 + cl] = (unsigned short)f2bf(acc[ct][r]);
  __syncthreads();
#pragma unroll
  for (int jj = 0; jj < 4; ++jj) {
    int u = t + jj * 256;
    int row = u >> 4, seg = u & 15;
    int gr = m0 + row;
    if (gr < Nrows)
      *(uint4*)&h1[(size_t)gr * HIDALL + seg * 8] = *(const uint4*)&hs[row][seg * 8];
  }
  {
    int row = t >> 2, h = t & 3;
    int gr = m0 + row;
    if (gr < Nrows) {
      float s = 0.f, dd = 0.f;
#pragma unroll
      for (int qq = 0; qq < 4; ++qq) {
        uint4 qv = *(const uint4*)&hs[row][h * 32 + qq * 8];
        int ab = h * 32 + qq * 8;
        s = fmaf(bflo(qv.x), attL[ab + 0], s);
        dd = fmaf(bflo(qv.x), attL[HIDALL + ab + 0], dd);
        s = fmaf(bfhi(qv.x), attL[ab + 1], s);
        dd = fmaf(bfhi(qv.x), attL[HIDALL + ab + 1], dd);
        s = fmaf(bflo(qv.y), attL[ab + 2], s);
        dd = fmaf(bflo(qv.y), attL[HIDALL + ab + 2], dd);
        s = fmaf(bfhi(qv.y), attL[ab + 3], s);
        dd = fmaf(bfhi(qv.y), attL[HIDALL + ab + 3], dd);
        s = fmaf(bflo(qv.z), attL[ab + 4], s);
        dd = fmaf(bflo(qv.z), attL[HIDALL + ab + 4], dd);
        s = fmaf(bfhi(qv.z), attL[ab + 5], s);
        dd = fmaf(bfhi(qv.z), attL[HIDALL + ab + 5], dd);
        s = fmaf(bflo(qv.w), attL[ab + 6], s);
        dd = fmaf(bflo(qv.w), attL[HIDALL + ab + 6], dd);
        s = fmaf(bfhi(qv.w), attL[ab + 7], s);
        dd = fmaf(bfhi(qv.w), attL[HIDALL + ab + 7], dd);
      }
      as1[(size_t)gr * 4 + h] = s * LOG2E;
      ad1[(size_t)gr * 4 + h] = dd * LOG2E;
    }
  }
}

// ------------ CSR build: fixed-capacity buckets (no histogram pass) ----------
#define S1_CH 8
__global__ __launch_bounds__(256) void stage1_k(const int* __restrict__ ei, int E,
                                                int* __restrict__ cursor,
                                                unsigned int* __restrict__ staging) {
  __shared__ int bh[MAXBUCK];
  __shared__ int bb[MAXBUCK];
  int t = threadIdx.x;
  if (t < MAXBUCK) bh[t] = 0;
  __syncthreads();
  int base = blockIdx.x * (256 * S1_CH);
  int s[S1_CH], d[S1_CH], r[S1_CH];
#pragma unroll
  for (int j = 0; j < S1_CH; ++j) {
    int e = base + t + j * 256;
    if (e < E) {
      s[j] = ei[e];
      d[j] = ei[(size_t)E + e];
      r[j] = atomicAdd(&bh[d[j] >> BSH], 1);
    } else {
      d[j] = -1;
    }
  }
  __syncthreads();
  if (t < MAXBUCK && bh[t]) bb[t] = atomicAdd(&cursor[t], bh[t]);
  __syncthreads();
#pragma unroll
  for (int j = 0; j < S1_CH; ++j) {
    if (d[j] >= 0) {
      int b = d[j] >> BSH;
      staging[(size_t)b * BCAP + bb[b] + r[j]] = ((unsigned)d[j] << 16) | (unsigned)s[j];
    }
  }
}

// stage 2: per bucket — degree count, padded scan (granularity 8) -> rowptr/
// rowend, sentinel pad fill, then scatter. esrc stores src*128.
__global__ __launch_bounds__(1024) void stage2_k(const unsigned int* __restrict__ staging,
                                                 const int* __restrict__ cursor,
                                                 int* __restrict__ rowptr,
                                                 int* __restrict__ rowend,
                                                 int* __restrict__ esrc, int n) {
  __shared__ int cnt[1 << BSH];
  __shared__ int pfx[1 << BSH];
  __shared__ int curw[1 << BSH];
  int b = blockIdx.x, nb0 = b << BSH, t = threadIdx.x;
  if (t < (1 << BSH)) cnt[t] = 0;
  __syncthreads();
  int fill = cursor[b];
  const unsigned int* st = staging + (size_t)b * BCAP;
  for (int i = t; i < fill; i += 1024)
    atomicAdd(&cnt[(st[i] >> 16) - nb0], 1);
  __syncthreads();
  if (t < (1 << BSH)) pfx[t] = (cnt[t] + 7) & ~7;
  __syncthreads();
  for (int o = 1; o < (1 << BSH); o <<= 1) {
    int v = 0;
    if (t < (1 << BSH) && t >= o) v = pfx[t - o];
    __syncthreads();
    if (t < (1 << BSH)) pfx[t] += v;
    __syncthreads();
  }
  if (t < (1 << BSH)) {
    int padDeg = (cnt[t] + 7) & ~7;
    int rp = b * PCAP + pfx[t] - padDeg;  // exclusive prefix
    int node = nb0 + t;
    if (node < n) {
      rowptr[node] = rp;
      rowend[node] = rp + padDeg;
    }
    curw[t] = rp;
    for (int i = cnt[t]; i < padDeg; ++i) esrc[rp + i] = n << 7;  // sentinel
  }
  __syncthreads();
  for (int i = t; i < fill; i += 1024) {
    unsigned v = st[i];
    int pos = atomicAdd(&curw[(v >> 16) - nb0], 1);
    esrc[pos] = (int)(v & 0xFFFFu) << 7;  // src * 128
  }
}

// ------- layer-1 aggregate: 2 waves per node, one-pass, pad-to-8 lists -------
// main loop: 32 unconditional slots/iter; tail: <=3 iters of 8 slots
// (wave-uniform bounds -> scalar branch). Weights via raw v_exp_f32.
#define A1PK(w_, u_)                                                            \
  {                                                                             \
    f32x2 wv = {w_, w_};                                                        \
    a2[0] = __builtin_elementwise_fma(wv, (f32x2){bflo(u_.x), bfhix(u_.x)}, a2[0]); \
    a2[1] = __builtin_elementwise_fma(wv, (f32x2){bflo(u_.y), bfhix(u_.y)}, a2[1]); \
    a2[2] = __builtin_elementwise_fma(wv, (f32x2){bflo(u_.z), bfhix(u_.z)}, a2[2]); \
    a2[3] = __builtin_elementwise_fma(wv, (f32x2){bflo(u_.w), bfhix(u_.w)}, a2[3]); \
  }

__global__ __launch_bounds__(256) void agg1_k(const int* __restrict__ rowptr,
                                              const int* __restrict__ rowend,
                                              const int* __restrict__ esrc,
                                              const unsigned short* __restrict__ h1,
                                              const float* __restrict__ as1,
                                              const float* __restrict__ ad1,
                                              const float* __restrict__ b1,
                                              unsigned short* __restrict__ hin2b, int n) {
  int wid = (blockIdx.x * 256 + threadIdx.x) >> 6;
  int lane = threadIdx.x & 63;
  if (wid >= 2 * n) return;
  int d = wid >> 1, half = wid & 1;
  int beg = rowptr[d], end = rowend[d];
  int fb8 = lane & 7, q = lane >> 3;
  int fOff = half * 64 + fb8 * 8;  // this lane's 8 features
  int h = half * 2 + (fb8 >> 2);   // head of those features
  float adv_h = ad1[4 * (size_t)d + h];
  float ws = fexp2(lrelu(as1[4 * (size_t)d + h] + adv_h));  // self weight
  float den = 0.f;
  f32x2 a2[4];
  a2[0] = a2[1] = a2[2] = a2[3] = (f32x2){0.f, 0.f};
  int end32 = beg + ((end - beg) & ~31);
  for (int i = beg + q; i < end32; i += 32) {
    int s1 = esrc[i];        // = src1 * 128
    int s2 = esrc[i + 8];
    int s3 = esrc[i + 16];
    int s4 = esrc[i + 24];
    float av1 = as1[((size_t)s1 >> 5) + h];
    float av2 = as1[((size_t)s2 >> 5) + h];
    float av3 = as1[((size_t)s3 >> 5) + h];
    float av4 = as1[((size_t)s4 >> 5) + h];
    uint4 u1 = *(const uint4*)&h1[(size_t)s1 + fOff];
    uint4 u2 = *(const uint4*)&h1[(size_t)s2 + fOff];
    uint4 u3 = *(const uint4*)&h1[(size_t)s3 + fOff];
    uint4 u4 = *(const uint4*)&h1[(size_t)s4 + fOff];
    float w1 = fexp2(lrelu(av1 + adv_h));
    float w2 = fexp2(lrelu(av2 + adv_h));
    float w3 = fexp2(lrelu(av3 + adv_h));
    float w4 = fexp2(lrelu(av4 + adv_h));
    den += (w1 + w2) + (w3 + w4);
    A1PK(w1, u1)
    A1PK(w2, u2)
    A1PK(w3, u3)
    A1PK(w4, u4)
  }
  for (int i = end32 + q; i < end; i += 8) {  // <=3 wave-uniform tail iters
    int s1 = esrc[i];
    float av1 = as1[((size_t)s1 >> 5) + h];
    uint4 u1 = *(const uint4*)&h1[(size_t)s1 + fOff];
    float w1 = fexp2(lrelu(av1 + adv_h));
    den += w1;
    A1PK(w1, u1)
  }
  float a[8] = {a2[0].x, a2[0].y, a2[1].x, a2[1].y,
                a2[2].x, a2[2].y, a2[3].x, a2[3].y};
  // reduce den + features across the 8 q-groups (lane bits 3..5)
#pragma unroll
  for (int off = 8; off <= 32; off <<= 1) den += __shfl_xor(den, off);
#pragma unroll
  for (int j = 0; j < 8; j++) {
    a[j] += __shfl_xor(a[j], 8);
    a[j] += __shfl_xor(a[j], 16);
    a[j] += __shfl_xor(a[j], 32);
  }
  if (q == 0) {
    uint4 ud = *(const uint4*)&h1[(size_t)d * HIDALL + fOff];
    den += ws;
    float inv = 1.f / (den + 1e-16f);
    const float* bp = &b1[fOff];
    float4 bb0 = *(const float4*)bp;
    float4 bb1 = *(const float4*)(bp + 4);
    float v[8];
    v[0] = fmaf(ws, bflo(ud.x), a[0]) * inv + bb0.x;
    v[1] = fmaf(ws, bfhi(ud.x), a[1]) * inv + bb0.y;
    v[2] = fmaf(ws, bflo(ud.y), a[2]) * inv + bb0.z;
    v[3] = fmaf(ws, bfhi(ud.y), a[3]) * inv + bb0.w;
    v[4] = fmaf(ws, bflo(ud.z), a[4]) * inv + bb1.x;
    v[5] = fmaf(ws, bfhi(ud.z), a[5]) * inv + bb1.y;
    v[6] = fmaf(ws, bflo(ud.w), a[6]) * inv + bb1.z;
    v[7] = fmaf(ws, bfhi(ud.w), a[7]) * inv + bb1.w;
#pragma unroll
    for (int j = 0; j < 8; j++) v[j] = v[j] > 0.f ? v[j] : (__expf(v[j]) - 1.f);
    uint4 pv;
    pv.x = pack2(v[0], v[1]);
    pv.y = pack2(v[2], v[3]);
    pv.z = pack2(v[4], v[5]);
    pv.w = pack2(v[6], v[7]);
    *(uint4*)&hin2b[(size_t)d * HIDALL + fOff] = pv;
  }
}

// ------ GEMM2 (+alpha2): h2x packed rows = hin2b @ W2, [N,128]@[128,16] ------
// h2x row (16 uints = 64 B): [0..7] 8x packed bf16 class pairs, [8] as2*log2e.
__global__ __launch_bounds__(256) void gemm2_k(const unsigned short* __restrict__ hin2b,
                                               const float* __restrict__ W2,
                                               const float* __restrict__ a2s,
                                               const float* __restrict__ a2d,
                                               unsigned int* __restrict__ h2x,
                                               float* __restrict__ ad2, int n) {
  __shared__ float wsm[128 * 16];
  __shared__ float hs[16][129];
  int t = threadIdx.x;
#pragma unroll
  for (int j = 0; j < 8; j++) wsm[t + j * 256] = W2[t + j * 256];
  int n0 = blockIdx.x * 16;
  const unsigned int* hw = (const unsigned int*)hin2b;  // row = 64 uints
#pragma unroll
  for (int j = 0; j < 4; j++) {
    int u = t + j * 256;  // 0..1023
    int r = u >> 6, cu = u & 63;
    int gn = n0 + r;
    unsigned v = (gn < n) ? hw[(size_t)gn * 64 + cu] : 0u;
    hs[r][cu * 2] = bflo(v);
    hs[r][cu * 2 + 1] = bfhi(v);
  }
  __syncthreads();
  int nl = t >> 4, c = t & 15;
  int gn = n0 + nl;
  float acc = 0.f;
#pragma unroll
  for (int k = 0; k < 128; k++) acc = fmaf(hs[nl][k], wsm[k * 16 + c], acc);
  float ps = acc * a2s[c];
  float pd = acc * a2d[c];
#pragma unroll
  for (int off = 8; off; off >>= 1) {
    ps += __shfl_xor(ps, off);
    pd += __shfl_xor(pd, off);
  }
  float other = __shfl_xor(acc, 1);
  if (gn < n) {
    if ((c & 1) == 0) h2x[(size_t)gn * 16 + (c >> 1)] = pack2(acc, other);
    if (c == 0) {
      h2x[(size_t)gn * 16 + 8] = __float_as_uint(ps * LOG2E);
      ad2[gn] = pd * LOG2E;
    }
  }
}

// --- layer-2 aggregate: one line/edge + bias + log_softmax; 8 lanes x 2 cls --
__global__ __launch_bounds__(256) void agg2_k(const int* __restrict__ rowptr,
                                              const int* __restrict__ rowend,
                                              const int* __restrict__ esrc,
                                              const unsigned int* __restrict__ h2x,
                                              const float* __restrict__ ad2,
                                              const float* __restrict__ b2,
                                              float* __restrict__ out, int n) {
  int wid = (blockIdx.x * 256 + threadIdx.x) >> 6;
  int lane = threadIdx.x & 63;
  if (wid >= n) return;
  int d = wid;
  int beg = rowptr[d], end = rowend[d];
  int c2 = lane & 7, q = lane >> 3;
  float advd = ad2[d];
  float asd = __uint_as_float(h2x[(size_t)d * 16 + 8]);
  float ws = fexp2(lrelu(asd + advd));
  float den = 0.f, a0 = 0.f, a1 = 0.f;
  int end16 = beg + ((end - beg) & ~15);
  for (int i = beg + q; i < end16; i += 16) {
    int sA = esrc[i];  // = srcA * 128
    const unsigned int* rA = &h2x[(size_t)sA >> 3];
    float avA = __uint_as_float(rA[8]);
    unsigned uA = rA[c2];
    int sB = esrc[i + 8];
    const unsigned int* rB = &h2x[(size_t)sB >> 3];
    float avB = __uint_as_float(rB[8]);
    unsigned uB = rB[c2];
    float wA = fexp2(lrelu(avA + advd));
    float wB = fexp2(lrelu(avB + advd));
    den += wA + wB;
    a0 = fmaf(wA, bflo(uA), a0); a1 = fmaf(wA, bfhix(uA), a1);
    a0 = fmaf(wB, bflo(uB), a0); a1 = fmaf(wB, bfhix(uB), a1);
  }
  for (int i = end16 + q; i < end; i += 8) {  // <=1 wave-uniform tail iter
    int sA = esrc[i];
    const unsigned int* rA = &h2x[(size_t)sA >> 3];
    float avA = __uint_as_float(rA[8]);
    unsigned uA = rA[c2];
    float wA = fexp2(lrelu(avA + advd));
    den += wA;
    a0 = fmaf(wA, bflo(uA), a0);
    a1 = fmaf(wA, bfhix(uA), a1);
  }
#pragma unroll
  for (int off = 8; off <= 32; off <<= 1) {
    den += __shfl_xor(den, off);
    a0 += __shfl_xor(a0, off);
    a1 += __shfl_xor(a1, off);
  }
  unsigned ud = h2x[(size_t)d * 16 + c2];
  den += ws;
  a0 = fmaf(ws, bflo(ud), a0);
  a1 = fmaf(ws, bfhi(ud), a1);
  float inv = 1.f / (den + 1e-16f);
  float l0 = a0 * inv + b2[2 * c2];
  float l1 = a1 * inv + b2[2 * c2 + 1];
  float m = fmaxf(l0, l1);
#pragma unroll
  for (int off = 1; off <= 4; off <<= 1) m = fmaxf(m, __shfl_xor(m, off));
  float se = __expf(l0 - m) + __expf(l1 - m);
#pragma unroll
  for (int off = 1; off <= 4; off <<= 1) se += __shfl_xor(se, off);
  float lg = logf(se);
  if (q == 0) {
    float2 r = make_float2(l0 - m - lg, l1 - m - lg);
    *(float2*)&out[(size_t)d * NCLS + 2 * c2] = r;
  }
}

extern "C" void kernel_launch(void* const* d_in, const int* in_sizes, int n_in,
                              void* d_out, int out_size, void* d_ws, size_t ws_size,
                              hipStream_t stream) {
  const float* x = (const float*)d_in[0];
  const int* ei = (const int*)d_in[1];  // int32 [2][E]: src row then dst row
  const float* W1 = (const float*)d_in[2];
  const float* asrc1 = (const float*)d_in[3];
  const float* adst1 = (const float*)d_in[4];
  const float* b1 = (const float*)d_in[5];
  const float* W2 = (const float*)d_in[6];
  const float* asrc2 = (const float*)d_in[7];
  const float* adst2 = (const float*)d_in[8];
  const float* b2 = (const float*)d_in[9];
  int N = in_sizes[0] / INC;  // 50000
  int E = in_sizes[1] / 2;    // 1600000
  float* out = (float*)d_out;
  int nbuck = (N + (1 << BSH) - 1) >> BSH;  // 98 for N=50000 (<= MAXBUCK)

  char* ws = (char*)d_ws;
  size_t off = 0;
  auto alloc = [&](size_t bytes) {
    void* p = ws + off;
    off = (off + bytes + 255) & ~(size_t)255;
    return p;
  };
  // h1/as1/h2x each have a sentinel row N (w=0 padding edges).
  unsigned short* h1 = (unsigned short*)alloc((size_t)(N + 1) * HIDALL * 2);
  unsigned short* hin2b = (unsigned short*)alloc((size_t)N * HIDALL * 2);
  float* as1 = (float*)alloc((size_t)(N + 1) * HEADS * 4);
  float* ad1 = (float*)alloc((size_t)N * HEADS * 4);
  unsigned int* h2x = (unsigned int*)alloc((size_t)(N + 1) * 16 * 4);
  float* ad2 = (float*)alloc((size_t)N * 4);
  int* rowptr = (int*)alloc((size_t)N * 4);
  int* rowend = (int*)alloc((size_t)N * 4);
  int* cursor = (int*)alloc(MAXBUCK * 4);
  int* esrc = (int*)alloc((size_t)MAXBUCK * PCAP * 4);
  unsigned int* staging = (unsigned int*)alloc((size_t)MAXBUCK * BCAP * 4);
  unsigned short* wtb = (unsigned short*)alloc((size_t)INC * HIDALL * 2);

  hipMemsetAsync(cursor, 0, MAXBUCK * 4, stream);
  wt_k<<<(INC * HIDALL) / 256, 256, 0, stream>>>(W1, wtb, as1, h2x, N);
  gemm1_k<<<(N + GM - 1) / GM, 256, 0, stream>>>(x, wtb, asrc1, adst1, h1, as1, ad1, N);
  stage1_k<<<(E + 256 * S1_CH - 1) / (256 * S1_CH), 256, 0, stream>>>(ei, E, cursor, staging);
  stage2_k<<<nbuck, 1024, 0, stream>>>(staging, cursor, rowptr, rowend, esrc, N);
  agg1_k<<<(2 * N + 3) / 4, 256, 0, stream>>>(rowptr, rowend, esrc, h1, as1, ad1, b1, hin2b, N);
  gemm2_k<<<(N + 15) / 16, 256, 0, stream>>>(hin2b, W2, asrc2, adst2, h2x, ad2, N);
  agg2_k<<<(N + 3) / 4, 256, 0, stream>>>(rowptr, rowend, esrc, h2x, ad2, b2, out, N);
}

// Round 19
// 167.436 us; speedup vs baseline: 1.0734x; 1.0434x over previous
//
#include <hip/hip_runtime.h>
#include <math.h>

#define INC   256
#define HIDALL 128   // HEADS*HID
#define HEADS 4
#define HID   32
#define NCLS  16
#define NEG   0.2f
#define BSH   9      // bucket = dst >> 9 (512 nodes per bucket)
#define MAXBUCK 128
#define BCAP  24576  // staging per-bucket capacity (mean fill 16384)
#define PCAP  40960  // esrc per-bucket padded capacity
#define LOG2E 1.44269504088896340736f

typedef __attribute__((ext_vector_type(8))) short short8_t;
typedef __attribute__((ext_vector_type(4))) float f32x4_t;
typedef __attribute__((ext_vector_type(2))) float f32x2;

__device__ __forceinline__ float lrelu(float v) { return fmaxf(v, NEG * v); }
__device__ __forceinline__ float fexp2(float v) { return __builtin_amdgcn_exp2f(v); }

// bf16 helpers; lo = low half (exact), hi approximated by leaving garbage low bits
__device__ __forceinline__ float bflo(unsigned int v) { return __uint_as_float(v << 16); }
__device__ __forceinline__ float bfhi(unsigned int v) { return __uint_as_float(v & 0xFFFF0000u); }
__device__ __forceinline__ float bfhix(unsigned int v) { return __uint_as_float(v); }  // ~2^-8 rel err
__device__ __forceinline__ unsigned int f2bf(float f) {  // RNE round to bf16 (as u16)
  unsigned int v = __float_as_uint(f);
  return (v + 0x7FFFu + ((v >> 16) & 1u)) >> 16;
}
__device__ __forceinline__ unsigned int pack2(float a, float b) {
  return f2bf(a) | (f2bf(b) << 16);
}

// ---- one-time W1 repack + sentinel rows (as1/h2x row N) + cursor zeroing ----
__global__ void wt_k(const float* __restrict__ W, unsigned short* __restrict__ wtb,
                     float* __restrict__ as1, unsigned int* __restrict__ h2x,
                     int* __restrict__ cursor, int n) {
  int i = blockIdx.x * 256 + threadIdx.x;  // 0..32767
  if (i < 4) as1[4 * (size_t)n + i] = -1e30f;     // agg1 sentinel: w = 0
  if (i >= 4 && i < 12) h2x[16 * (size_t)n + (i - 4)] = 0u;  // zero class pairs
  if (i == 12) h2x[16 * (size_t)n + 8] = __float_as_uint(-1e30f);  // agg2 sentinel
  if (i >= 16 && i < 16 + MAXBUCK) cursor[i - 16] = 0;
  int k = i >> 7, c = i & 127;
  wtb[(((k >> 5) * 4 + ((k >> 3) & 3)) * 128 + c) * 8 + (k & 7)] =
      (unsigned short)f2bf(W[i]);
}

// ------- GEMM1 (bf16 MFMA) + fused alpha1: h1(bf16) = x @ W1 -----------------
// alpha dots are pre-scaled by log2(e) so agg kernels can use raw v_exp_f32.
#define GM 64
__global__ __launch_bounds__(256) void gemm1_k(const float* __restrict__ x,
                                               const unsigned short* __restrict__ wtb,
                                               const float* __restrict__ asrc,
                                               const float* __restrict__ adst,
                                               unsigned short* __restrict__ h1,
                                               float* __restrict__ as1,
                                               float* __restrict__ ad1, int Nrows) {
  __shared__ unsigned short xs2[4][GM][8];    // A tiles: [kgrp][row][k&7]
  __shared__ unsigned short wsm2[4][128][8];  // B tiles: [kgrp][col][k&7]
  __shared__ unsigned short hs[GM][128];      // C out-tile (bf16)
  __shared__ float attL[2 * HIDALL];          // asrc | adst
  int t = threadIdx.x;
  int m0 = blockIdx.x * GM;
  int w = t >> 6, lane = t & 63;
  if (t < HIDALL) attL[t] = asrc[t];
  else attL[t] = adst[t - HIDALL];

  f32x4_t acc[8];
#pragma unroll
  for (int ct = 0; ct < 8; ++ct) acc[ct] = (f32x4_t){0.f, 0.f, 0.f, 0.f};

  int rowA = w * 16 + (lane & 15);
  int kg = lane >> 4;
  int cl = lane & 15;

  for (int ks = 0; ks < 8; ++ks) {
    int kc = ks * 32;
#pragma unroll
    for (int jj = 0; jj < 2; ++jj) {
      int u = t + jj * 256;            // float4 unit
      int row = u >> 3, c4i = u & 7;   // k-offset = c4i*4
      int gr = m0 + row;
      float4 v = (gr < Nrows) ? *(const float4*)&x[(size_t)gr * INC + kc + c4i * 4]
                              : make_float4(0.f, 0.f, 0.f, 0.f);
      uint2 p;
      p.x = pack2(v.x, v.y);
      p.y = pack2(v.z, v.w);
      *(uint2*)&xs2[c4i >> 1][row][(c4i & 1) * 4] = p;
    }
    const unsigned short* wt = wtb + ks * 4096;
#pragma unroll
    for (int jj = 0; jj < 2; ++jj) {
      int u = t + jj * 256;
      *(uint4*)&((unsigned short*)wsm2)[u * 8] = *(const uint4*)&wt[u * 8];
    }
    __syncthreads();
    short8_t a = *(const short8_t*)&xs2[kg][rowA][0];
#pragma unroll
    for (int ct = 0; ct < 8; ++ct) {
      short8_t b = *(const short8_t*)&wsm2[kg][ct * 16 + cl][0];
      acc[ct] = __builtin_amdgcn_mfma_f32_16x16x32_bf16(a, b, acc[ct], 0, 0, 0);
    }
    __syncthreads();
  }
#pragma unroll
  for (int ct = 0; ct < 8; ++ct)
#pragma unroll
    for (int r = 0; r < 4; ++r)
      hs[w * 16 + (lane >> 4) * 4 + r][ct * 16 + cl] = (unsigned short)f2bf(acc[ct][r]);
  __syncthreads();
#pragma unroll
  for (int jj = 0; jj < 4; ++jj) {
    int u = t + jj * 256;
    int row = u >> 4, seg = u & 15;
    int gr = m0 + row;
    if (gr < Nrows)
      *(uint4*)&h1[(size_t)gr * HIDALL + seg * 8] = *(const uint4*)&hs[row][seg * 8];
  }
  {
    int row = t >> 2, h = t & 3;
    int gr = m0 + row;
    if (gr < Nrows) {
      float s = 0.f, dd = 0.f;
#pragma unroll
      for (int qq = 0; qq < 4; ++qq) {
        uint4 qv = *(const uint4*)&hs[row][h * 32 + qq * 8];
        int ab = h * 32 + qq * 8;
        s = fmaf(bflo(qv.x), attL[ab + 0], s);
        dd = fmaf(bflo(qv.x), attL[HIDALL + ab + 0], dd);
        s = fmaf(bfhi(qv.x), attL[ab + 1], s);
        dd = fmaf(bfhi(qv.x), attL[HIDALL + ab + 1], dd);
        s = fmaf(bflo(qv.y), attL[ab + 2], s);
        dd = fmaf(bflo(qv.y), attL[HIDALL + ab + 2], dd);
        s = fmaf(bfhi(qv.y), attL[ab + 3], s);
        dd = fmaf(bfhi(qv.y), attL[HIDALL + ab + 3], dd);
        s = fmaf(bflo(qv.z), attL[ab + 4], s);
        dd = fmaf(bflo(qv.z), attL[HIDALL + ab + 4], dd);
        s = fmaf(bfhi(qv.z), attL[ab + 5], s);
        dd = fmaf(bfhi(qv.z), attL[HIDALL + ab + 5], dd);
        s = fmaf(bflo(qv.w), attL[ab + 6], s);
        dd = fmaf(bflo(qv.w), attL[HIDALL + ab + 6], dd);
        s = fmaf(bfhi(qv.w), attL[ab + 7], s);
        dd = fmaf(bfhi(qv.w), attL[HIDALL + ab + 7], dd);
      }
      as1[(size_t)gr * 4 + h] = s * LOG2E;
      ad1[(size_t)gr * 4 + h] = dd * LOG2E;
    }
  }
}

// ------------ CSR build: fixed-capacity buckets (no histogram pass) ----------
#define S1_CH 16
__global__ __launch_bounds__(256) void stage1_k(const int* __restrict__ ei, int E,
                                                int* __restrict__ cursor,
                                                unsigned int* __restrict__ staging) {
  __shared__ int bh[MAXBUCK];
  __shared__ int bb[MAXBUCK];
  int t = threadIdx.x;
  if (t < MAXBUCK) bh[t] = 0;
  __syncthreads();
  int base = blockIdx.x * (256 * S1_CH);
  int s[S1_CH], d[S1_CH], r[S1_CH];
#pragma unroll
  for (int j = 0; j < S1_CH; ++j) {
    int e = base + t + j * 256;
    if (e < E) {
      s[j] = ei[e];
      d[j] = ei[(size_t)E + e];
      r[j] = atomicAdd(&bh[d[j] >> BSH], 1);
    } else {
      d[j] = -1;
    }
  }
  __syncthreads();
  if (t < MAXBUCK && bh[t]) bb[t] = atomicAdd(&cursor[t], bh[t]);
  __syncthreads();
#pragma unroll
  for (int j = 0; j < S1_CH; ++j) {
    if (d[j] >= 0) {
      int b = d[j] >> BSH;
      staging[(size_t)b * BCAP + bb[b] + r[j]] = ((unsigned)d[j] << 16) | (unsigned)s[j];
    }
  }
}

// stage 2: per bucket — degree count, padded scan (granularity 8) -> rowptr/
// rowend, sentinel pad fill, then scatter. esrc stores src*128.
__global__ __launch_bounds__(1024) void stage2_k(const unsigned int* __restrict__ staging,
                                                 const int* __restrict__ cursor,
                                                 int* __restrict__ rowptr,
                                                 int* __restrict__ rowend,
                                                 int* __restrict__ esrc, int n) {
  __shared__ int cnt[1 << BSH];
  __shared__ int pfx[1 << BSH];
  __shared__ int curw[1 << BSH];
  int b = blockIdx.x, nb0 = b << BSH, t = threadIdx.x;
  if (t < (1 << BSH)) cnt[t] = 0;
  __syncthreads();
  int fill = cursor[b];
  const unsigned int* st = staging + (size_t)b * BCAP;
  for (int i = t; i < fill; i += 1024)
    atomicAdd(&cnt[(st[i] >> 16) - nb0], 1);
  __syncthreads();
  if (t < (1 << BSH)) pfx[t] = (cnt[t] + 7) & ~7;
  __syncthreads();
  for (int o = 1; o < (1 << BSH); o <<= 1) {
    int v = 0;
    if (t < (1 << BSH) && t >= o) v = pfx[t - o];
    __syncthreads();
    if (t < (1 << BSH)) pfx[t] += v;
    __syncthreads();
  }
  if (t < (1 << BSH)) {
    int padDeg = (cnt[t] + 7) & ~7;
    int rp = b * PCAP + pfx[t] - padDeg;  // exclusive prefix
    int node = nb0 + t;
    if (node < n) {
      rowptr[node] = rp;
      rowend[node] = rp + padDeg;
    }
    curw[t] = rp;
    for (int i = cnt[t]; i < padDeg; ++i) esrc[rp + i] = n << 7;  // sentinel
  }
  __syncthreads();
  for (int i = t; i < fill; i += 1024) {
    unsigned v = st[i];
    int pos = atomicAdd(&curw[(v >> 16) - nb0], 1);
    esrc[pos] = (int)(v & 0xFFFFu) << 7;  // src * 128
  }
}

// ------- layer-1 aggregate: 2 waves per node, one-pass, pad-to-8 lists -------
// lane q owns slots 4q..4q+3 -> ONE uint4 esrc load per 32-slot iter.
// main loop: 32 unconditional slots/iter; tail: <=3 iters of 8 slots.
#define A1PK(w_, u_)                                                            \
  {                                                                             \
    f32x2 wv = {w_, w_};                                                        \
    a2[0] = __builtin_elementwise_fma(wv, (f32x2){bflo(u_.x), bfhix(u_.x)}, a2[0]); \
    a2[1] = __builtin_elementwise_fma(wv, (f32x2){bflo(u_.y), bfhix(u_.y)}, a2[1]); \
    a2[2] = __builtin_elementwise_fma(wv, (f32x2){bflo(u_.z), bfhix(u_.z)}, a2[2]); \
    a2[3] = __builtin_elementwise_fma(wv, (f32x2){bflo(u_.w), bfhix(u_.w)}, a2[3]); \
  }

__global__ __launch_bounds__(256) void agg1_k(const int* __restrict__ rowptr,
                                              const int* __restrict__ rowend,
                                              const int* __restrict__ esrc,
                                              const unsigned short* __restrict__ h1,
                                              const float* __restrict__ as1,
                                              const float* __restrict__ ad1,
                                              const float* __restrict__ b1,
                                              unsigned short* __restrict__ hin2b, int n) {
  int wid = (blockIdx.x * 256 + threadIdx.x) >> 6;
  int lane = threadIdx.x & 63;
  if (wid >= 2 * n) return;
  int d = wid >> 1, half = wid & 1;
  int beg = rowptr[d], end = rowend[d];
  int fb8 = lane & 7, q = lane >> 3;
  int fOff = half * 64 + fb8 * 8;  // this lane's 8 features
  int h = half * 2 + (fb8 >> 2);   // head of those features
  float adv_h = ad1[4 * (size_t)d + h];
  float ws = fexp2(lrelu(as1[4 * (size_t)d + h] + adv_h));  // self weight
  float den = 0.f;
  f32x2 a2[4];
  a2[0] = a2[1] = a2[2] = a2[3] = (f32x2){0.f, 0.f};
  int end32 = beg + ((end - beg) & ~31);
  for (int i = beg + q * 4; i < end32; i += 32) {
    int4 sv = *(const int4*)&esrc[i];  // 4 contiguous slots (src*128 each)
    float av1 = as1[((size_t)sv.x >> 5) + h];
    float av2 = as1[((size_t)sv.y >> 5) + h];
    float av3 = as1[((size_t)sv.z >> 5) + h];
    float av4 = as1[((size_t)sv.w >> 5) + h];
    uint4 u1 = *(const uint4*)&h1[(size_t)sv.x + fOff];
    uint4 u2 = *(const uint4*)&h1[(size_t)sv.y + fOff];
    uint4 u3 = *(const uint4*)&h1[(size_t)sv.z + fOff];
    uint4 u4 = *(const uint4*)&h1[(size_t)sv.w + fOff];
    float w1 = fexp2(lrelu(av1 + adv_h));
    float w2 = fexp2(lrelu(av2 + adv_h));
    float w3 = fexp2(lrelu(av3 + adv_h));
    float w4 = fexp2(lrelu(av4 + adv_h));
    den += (w1 + w2) + (w3 + w4);
    A1PK(w1, u1)
    A1PK(w2, u2)
    A1PK(w3, u3)
    A1PK(w4, u4)
  }
  for (int i = end32 + q; i < end; i += 8) {  // <=3 wave-uniform tail iters
    int s1 = esrc[i];
    float av1 = as1[((size_t)s1 >> 5) + h];
    uint4 u1 = *(const uint4*)&h1[(size_t)s1 + fOff];
    float w1 = fexp2(lrelu(av1 + adv_h));
    den += w1;
    A1PK(w1, u1)
  }
  float a[8] = {a2[0].x, a2[0].y, a2[1].x, a2[1].y,
                a2[2].x, a2[2].y, a2[3].x, a2[3].y};
  // reduce den + features across the 8 q-groups (lane bits 3..5)
#pragma unroll
  for (int off = 8; off <= 32; off <<= 1) den += __shfl_xor(den, off);
#pragma unroll
  for (int j = 0; j < 8; j++) {
    a[j] += __shfl_xor(a[j], 8);
    a[j] += __shfl_xor(a[j], 16);
    a[j] += __shfl_xor(a[j], 32);
  }
  if (q == 0) {
    uint4 ud = *(const uint4*)&h1[(size_t)d * HIDALL + fOff];
    den += ws;
    float inv = 1.f / (den + 1e-16f);
    const float* bp = &b1[fOff];
    float4 bb0 = *(const float4*)bp;
    float4 bb1 = *(const float4*)(bp + 4);
    float v[8];
    v[0] = fmaf(ws, bflo(ud.x), a[0]) * inv + bb0.x;
    v[1] = fmaf(ws, bfhi(ud.x), a[1]) * inv + bb0.y;
    v[2] = fmaf(ws, bflo(ud.y), a[2]) * inv + bb0.z;
    v[3] = fmaf(ws, bfhi(ud.y), a[3]) * inv + bb0.w;
    v[4] = fmaf(ws, bflo(ud.z), a[4]) * inv + bb1.x;
    v[5] = fmaf(ws, bfhi(ud.z), a[5]) * inv + bb1.y;
    v[6] = fmaf(ws, bflo(ud.w), a[6]) * inv + bb1.z;
    v[7] = fmaf(ws, bfhi(ud.w), a[7]) * inv + bb1.w;
#pragma unroll
    for (int j = 0; j < 8; j++) v[j] = v[j] > 0.f ? v[j] : (__expf(v[j]) - 1.f);
    uint4 pv;
    pv.x = pack2(v[0], v[1]);
    pv.y = pack2(v[2], v[3]);
    pv.z = pack2(v[4], v[5]);
    pv.w = pack2(v[6], v[7]);
    *(uint4*)&hin2b[(size_t)d * HIDALL + fOff] = pv;
  }
}

// ------ GEMM2 (+alpha2): h2x packed rows = hin2b @ W2, [N,128]@[128,16] ------
// h2x row (16 uints = 64 B): [0..7] 8x packed bf16 class pairs, [8] as2*log2e.
__global__ __launch_bounds__(256) void gemm2_k(const unsigned short* __restrict__ hin2b,
                                               const float* __restrict__ W2,
                                               const float* __restrict__ a2s,
                                               const float* __restrict__ a2d,
                                               unsigned int* __restrict__ h2x,
                                               float* __restrict__ ad2, int n) {
  __shared__ float wsm[128 * 16];
  __shared__ float hs[16][129];
  int t = threadIdx.x;
#pragma unroll
  for (int j = 0; j < 8; j++) wsm[t + j * 256] = W2[t + j * 256];
  int n0 = blockIdx.x * 16;
  const unsigned int* hw = (const unsigned int*)hin2b;  // row = 64 uints
#pragma unroll
  for (int j = 0; j < 4; j++) {
    int u = t + j * 256;  // 0..1023
    int r = u >> 6, cu = u & 63;
    int gn = n0 + r;
    unsigned v = (gn < n) ? hw[(size_t)gn * 64 + cu] : 0u;
    hs[r][cu * 2] = bflo(v);
    hs[r][cu * 2 + 1] = bfhi(v);
  }
  __syncthreads();
  int nl = t >> 4, c = t & 15;
  int gn = n0 + nl;
  float acc = 0.f;
#pragma unroll
  for (int k = 0; k < 128; k++) acc = fmaf(hs[nl][k], wsm[k * 16 + c], acc);
  float ps = acc * a2s[c];
  float pd = acc * a2d[c];
#pragma unroll
  for (int off = 8; off; off >>= 1) {
    ps += __shfl_xor(ps, off);
    pd += __shfl_xor(pd, off);
  }
  float other = __shfl_xor(acc, 1);
  if (gn < n) {
    if ((c & 1) == 0) h2x[(size_t)gn * 16 + (c >> 1)] = pack2(acc, other);
    if (c == 0) {
      h2x[(size_t)gn * 16 + 8] = __float_as_uint(ps * LOG2E);
      ad2[gn] = pd * LOG2E;
    }
  }
}

// --- layer-2 aggregate: one line/edge + bias + log_softmax; 8 lanes x 2 cls --
// lane q owns slots 2q, 2q+1 -> one uint2 esrc load per 16-slot iter.
__global__ __launch_bounds__(256) void agg2_k(const int* __restrict__ rowptr,
                                              const int* __restrict__ rowend,
                                              const int* __restrict__ esrc,
                                              const unsigned int* __restrict__ h2x,
                                              const float* __restrict__ ad2,
                                              const float* __restrict__ b2,
                                              float* __restrict__ out, int n) {
  int wid = (blockIdx.x * 256 + threadIdx.x) >> 6;
  int lane = threadIdx.x & 63;
  if (wid >= n) return;
  int d = wid;
  int beg = rowptr[d], end = rowend[d];
  int c2 = lane & 7, q = lane >> 3;
  float advd = ad2[d];
  float asd = __uint_as_float(h2x[(size_t)d * 16 + 8]);
  float ws = fexp2(lrelu(asd + advd));
  float den = 0.f, a0 = 0.f, a1 = 0.f;
  int end16 = beg + ((end - beg) & ~15);
  for (int i = beg + q * 2; i < end16; i += 16) {
    int2 sv = *(const int2*)&esrc[i];
    const unsigned int* rA = &h2x[(size_t)sv.x >> 3];
    const unsigned int* rB = &h2x[(size_t)sv.y >> 3];
    float avA = __uint_as_float(rA[8]);
    unsigned uA = rA[c2];
    float avB = __uint_as_float(rB[8]);
    unsigned uB = rB[c2];
    float wA = fexp2(lrelu(avA + advd));
    float wB = fexp2(lrelu(avB + advd));
    den += wA + wB;
    a0 = fmaf(wA, bflo(uA), a0); a1 = fmaf(wA, bfhix(uA), a1);
    a0 = fmaf(wB, bflo(uB), a0); a1 = fmaf(wB, bfhix(uB), a1);
  }
  for (int i = end16 + q; i < end; i += 8) {  // <=1 wave-uniform tail iter
    int sA = esrc[i];
    const unsigned int* rA = &h2x[(size_t)sA >> 3];
    float avA = __uint_as_float(rA[8]);
    unsigned uA = rA[c2];
    float wA = fexp2(lrelu(avA + advd));
    den += wA;
    a0 = fmaf(wA, bflo(uA), a0);
    a1 = fmaf(wA, bfhix(uA), a1);
  }
#pragma unroll
  for (int off = 8; off <= 32; off <<= 1) {
    den += __shfl_xor(den, off);
    a0 += __shfl_xor(a0, off);
    a1 += __shfl_xor(a1, off);
  }
  unsigned ud = h2x[(size_t)d * 16 + c2];
  den += ws;
  a0 = fmaf(ws, bflo(ud), a0);
  a1 = fmaf(ws, bfhi(ud), a1);
  float inv = 1.f / (den + 1e-16f);
  float l0 = a0 * inv + b2[2 * c2];
  float l1 = a1 * inv + b2[2 * c2 + 1];
  float m = fmaxf(l0, l1);
#pragma unroll
  for (int off = 1; off <= 4; off <<= 1) m = fmaxf(m, __shfl_xor(m, off));
  float se = __expf(l0 - m) + __expf(l1 - m);
#pragma unroll
  for (int off = 1; off <= 4; off <<= 1) se += __shfl_xor(se, off);
  float lg = logf(se);
  if (q == 0) {
    float2 r = make_float2(l0 - m - lg, l1 - m - lg);
    *(float2*)&out[(size_t)d * NCLS + 2 * c2] = r;
  }
}

extern "C" void kernel_launch(void* const* d_in, const int* in_sizes, int n_in,
                              void* d_out, int out_size, void* d_ws, size_t ws_size,
                              hipStream_t stream) {
  const float* x = (const float*)d_in[0];
  const int* ei = (const int*)d_in[1];  // int32 [2][E]: src row then dst row
  const float* W1 = (const float*)d_in[2];
  const float* asrc1 = (const float*)d_in[3];
  const float* adst1 = (const float*)d_in[4];
  const float* b1 = (const float*)d_in[5];
  const float* W2 = (const float*)d_in[6];
  const float* asrc2 = (const float*)d_in[7];
  const float* adst2 = (const float*)d_in[8];
  const float* b2 = (const float*)d_in[9];
  int N = in_sizes[0] / INC;  // 50000
  int E = in_sizes[1] / 2;    // 1600000
  float* out = (float*)d_out;
  int nbuck = (N + (1 << BSH) - 1) >> BSH;  // 98 for N=50000 (<= MAXBUCK)

  char* ws = (char*)d_ws;
  size_t off = 0;
  auto alloc = [&](size_t bytes) {
    void* p = ws + off;
    off = (off + bytes + 255) & ~(size_t)255;
    return p;
  };
  // h1/as1/h2x each have a sentinel row N (w=0 padding edges).
  unsigned short* h1 = (unsigned short*)alloc((size_t)(N + 1) * HIDALL * 2);
  unsigned short* hin2b = (unsigned short*)alloc((size_t)N * HIDALL * 2);
  float* as1 = (float*)alloc((size_t)(N + 1) * HEADS * 4);
  float* ad1 = (float*)alloc((size_t)N * HEADS * 4);
  unsigned int* h2x = (unsigned int*)alloc((size_t)(N + 1) * 16 * 4);
  float* ad2 = (float*)alloc((size_t)N * 4);
  int* rowptr = (int*)alloc((size_t)N * 4);
  int* rowend = (int*)alloc((size_t)N * 4);
  int* cursor = (int*)alloc(MAXBUCK * 4);
  int* esrc = (int*)alloc((size_t)MAXBUCK * PCAP * 4);
  unsigned int* staging = (unsigned int*)alloc((size_t)MAXBUCK * BCAP * 4);
  unsigned short* wtb = (unsigned short*)alloc((size_t)INC * HIDALL * 2);

  wt_k<<<(INC * HIDALL) / 256, 256, 0, stream>>>(W1, wtb, as1, h2x, cursor, N);
  gemm1_k<<<(N + GM - 1) / GM, 256, 0, stream>>>(x, wtb, asrc1, adst1, h1, as1, ad1, N);
  stage1_k<<<(E + 256 * S1_CH - 1) / (256 * S1_CH), 256, 0, stream>>>(ei, E, cursor, staging);
  stage2_k<<<nbuck, 1024, 0, stream>>>(staging, cursor, rowptr, rowend, esrc, N);
  agg1_k<<<(2 * N + 3) / 4, 256, 0, stream>>>(rowptr, rowend, esrc, h1, as1, ad1, b1, hin2b, N);
  gemm2_k<<<(N + 15) / 16, 256, 0, stream>>>(hin2b, W2, asrc2, adst2, h2x, ad2, N);
  agg2_k<<<(N + 3) / 4, 256, 0, stream>>>(rowptr, rowend, esrc, h2x, ad2, b2, out, N);
}